// Round 2
// baseline (771.800 us; speedup 1.0000x reference)
//
#include <hip/hip_runtime.h>

// Problem: B=32,T=12,N=325,D=64,H=4,HD=16,M_SP=32,M_T=6, SCALE=0.25
// Inputs fp32 (+ int32 mode lists); output fp32.
//
// Key identities used:
//  * temporal branch: softmax axis == mean axis  =>  out = vf/6. Whole branch is
//    v=x@Wv_t^T (fake (n',t') reshape r = n'*12+t'), drop Nyquist of 12-pt rfft, /6:
//    te[t'] = (v[t'] - (-1)^{t'} * (sum_s (-1)^s v[s]) / 12) / 6
//  * rfft over n commutes with channel linear => one DFT of x, then 64x64 matmuls.
//  * ||x@W^T||_F^2 = sum_{e,e'} (W^T W)[e,e'] * G[e,e'],  G = sum_rows x x^T.
//  * GCN: Wc = W_mlp @ W_fc1 folded; out = A_rownorm @ (x @ Wc^T) + b.

// ---- workspace layout (float offsets) ----
constexpr size_t OFF_G    = 0;          // 4096   Gram (memset each launch, atomic-accumulated)
constexpr size_t OFF_NORM = 4096;       // 16     [0]=1/||q_s||, [1]=1/||k_s||
constexpr size_t OFF_WC   = 4112;       // 4096   Wc = Wmlp@Wfc1
constexpr size_t OFF_WQA  = 8208;       // 15872  |weights_Q|
constexpr size_t OFF_AN   = 24080;      // 105625 row-normalized adj
constexpr size_t OFF_FCOS = 129712;     // 10400  cos(2pi f_j n/325)
constexpr size_t OFF_FSIN = 140112;     // 10400
constexpr size_t OFF_ICOS = 150512;     // 10400  wgt_j/325 * cos
constexpr size_t OFF_ISIN = 160912;     // 10400
constexpr size_t OFF_OF   = 171312;     // 1572864  spatial out-spectrum [bt][j][d] float2
constexpr size_t OFF_XC   = 1744176;    // 7987200  x @ Wc^T
constexpr size_t OFF_VT   = 9731376;    // 7987200  x @ Wv_t^T
constexpr size_t OFF_ALT  = 17718576;   // 665600   alternating sums per fake-time group
// total = 18,384,176 floats = 73.5 MB

// =====================  K1: Gram matrix G = sum_rows x x^T  =====================
__global__ __launch_bounds__(256) void k_gram(const float* __restrict__ x,
                                              float* __restrict__ ws) {
  __shared__ __align__(16) float xs[2048];   // [32 rows][64]
  const int tid = threadIdx.x;
  const int e0 = (tid >> 4) << 2;
  const int f0 = (tid & 15) << 2;
  float acc[4][4] = {};
  const int ROWS = 124800;  // B*T*N
  for (int r0 = blockIdx.x * 32; r0 < ROWS; r0 += gridDim.x * 32) {
    const float4* src = (const float4*)(x + (size_t)r0 * 64);
    float4* dst = (float4*)xs;
    for (int i = tid; i < 512; i += 256) dst[i] = src[i];
    __syncthreads();
    for (int rr = 0; rr < 32; ++rr) {
      float a[4], b[4];
#pragma unroll
      for (int i = 0; i < 4; ++i) a[i] = xs[rr * 64 + e0 + i];
#pragma unroll
      for (int j = 0; j < 4; ++j) b[j] = xs[rr * 64 + f0 + j];
#pragma unroll
      for (int i = 0; i < 4; ++i)
#pragma unroll
        for (int j = 0; j < 4; ++j) acc[i][j] = fmaf(a[i], b[j], acc[i][j]);
    }
    __syncthreads();
  }
#pragma unroll
  for (int i = 0; i < 4; ++i)
#pragma unroll
    for (int j = 0; j < 4; ++j)
      atomicAdd(&ws[OFF_G + (size_t)(e0 + i) * 64 + f0 + j], acc[i][j]);
}

// ===========  K2: norms, Wc, |wQ|, adj row-norm, twiddle tables  ===========
__global__ __launch_bounds__(256) void k_prep(const float* __restrict__ adj,
                                              const float* __restrict__ Wq,
                                              const float* __restrict__ Wk,
                                              const float* __restrict__ Wmlp,
                                              const float* __restrict__ Wfc1,
                                              const float* __restrict__ wQ,
                                              const int* __restrict__ sp_modes,
                                              float* __restrict__ ws) {
  __shared__ float ldsw[2 * 64 * 65];
  __shared__ float partial[4];
  __shared__ float red[256];
  const int tid = threadIdx.x;
  const int blk = blockIdx.x;
  if (blk == 0) {
    // ||q||^2 = sum_d Wq[d,:] G Wq[d,:]^T  (same for k); 4 waves: (q lo/hi e, k lo/hi e)
    for (int i = tid; i < 4096; i += 256) {
      int dd = i >> 6, e = i & 63;
      ldsw[dd * 65 + e] = Wq[i];
      ldsw[4160 + dd * 65 + e] = Wk[i];
    }
    __syncthreads();
    const int wave = tid >> 6, lane = tid & 63;
    const float* Wl = ldsw + ((wave >= 2) ? 4160 : 0);
    const int e0 = (wave & 1) * 32;
    float s = 0.f;
    for (int e = e0; e < e0 + 32; ++e) {
      const float* Gr = ws + OFF_G + (size_t)e * 64;
      float t = 0.f;
      for (int e2 = 0; e2 < 64; ++e2) t = fmaf(Gr[e2], Wl[lane * 65 + e2], t);
      s += Wl[lane * 65 + e] * t;
    }
    for (int off = 32; off > 0; off >>= 1) s += __shfl_down(s, off);
    if (lane == 0) partial[wave] = s;
    __syncthreads();
    if (tid == 0) {
      ws[OFF_NORM + 0] = rsqrtf(partial[0] + partial[1]);
      ws[OFF_NORM + 1] = rsqrtf(partial[2] + partial[3]);
    }
  } else if (blk == 1) {
    for (int o = tid; o < 4096; o += 256) {
      int g = o >> 6, dd = o & 63;
      float s = 0.f;
      for (int e = 0; e < 64; ++e)
        s = fmaf(Wmlp[g * 64 + e], Wfc1[e * 64 + dd], s);
      ws[OFF_WC + o] = s;
    }
  } else if (blk < 10) {
    for (int i = (blk - 2) * 256 + tid; i < 15872; i += 2048)
      ws[OFF_WQA + i] = fabsf(wQ[i]);
  } else if (blk < 335) {
    const int n = blk - 10;
    float p = 0.f;
    for (int k = tid; k < 325; k += 256) p += adj[n * 325 + k];
    red[tid] = p;
    __syncthreads();
    for (int s2 = 128; s2 > 0; s2 >>= 1) {
      if (tid < s2) red[tid] += red[tid + s2];
      __syncthreads();
    }
    const float inv = 1.f / red[0];
    for (int k = tid; k < 325; k += 256)
      ws[OFF_AN + (size_t)n * 325 + k] = adj[n * 325 + k] * inv;
  } else {
    const int j = blk - 335;  // < 32
    const int f = sp_modes[j];
    const float wgt = (f == 0) ? 1.f : 2.f;
    for (int n = tid; n < 325; n += 256) {
      int mm = (f * n) % 325;                 // exact range reduction
      float th = 6.283185307179586f * (float)mm * (1.f / 325.f);
      float c = cosf(th), s = sinf(th);
      ws[OFF_FCOS + j * 325 + n] = c;
      ws[OFF_FSIN + j * 325 + n] = s;
      ws[OFF_ICOS + j * 325 + n] = wgt * (1.f / 325.f) * c;
      ws[OFF_ISIN + j * 325 + n] = wgt * (1.f / 325.f) * s;
    }
  }
}

// =======  K3: fused spatial branch per (b,t): DFT -> q/k/v -> attention -> of  =======
// LDS staging uses fp16 (_Float16) to fit in 58 KB; all accumulation fp32.
__global__ __launch_bounds__(256) void k_spatial(const float* __restrict__ x,
                                                 const float* __restrict__ Wq,
                                                 const float* __restrict__ Wk,
                                                 const float* __restrict__ Wv,
                                                 float* __restrict__ ws) {
  __shared__ __align__(16) float smem[14496];       // 57,984 B
  float* xf_re = smem;                              // [32][64]
  float* xf_im = smem + 2048;
  _Float16* xs = (_Float16*)(smem + 4096);          // [325][64] (ph1-2)
  _Float16* wlds = (_Float16*)(smem + 4096);        // 3x[64][66] (ph3)
  float* vf_re = smem + 4096;                       // (ph3c+) overwrites wlds
  float* vf_im = smem + 6144;
  float* wbar = smem + 8192;
  float* absq = smem;                               // alias xf_re after ph3b
  float* absk = smem + 2048;

  const int tid = threadIdx.x;
  const int bt = blockIdx.x;

  {  // ph1: stage x[b,t] as fp16
    const float4* src = (const float4*)(x + (size_t)bt * 20800);
    for (int i = tid; i < 5200; i += 256) {
      float4 f = src[i];
      xs[4 * i + 0] = (_Float16)f.x;
      xs[4 * i + 1] = (_Float16)f.y;
      xs[4 * i + 2] = (_Float16)f.z;
      xs[4 * i + 3] = (_Float16)f.w;
    }
  }
  __syncthreads();

  {  // ph2: xf[f][e] = sum_n x[n][e] e^{-i 2pi f_j n/325}
    const int wave = tid >> 6, e = tid & 63;
    for (int it = 0; it < 8; ++it) {
      const int f = wave + (it << 2);
      const float* fc = ws + OFF_FCOS + f * 325;
      const float* fs = ws + OFF_FSIN + f * 325;
      float re = 0.f, im = 0.f;
      for (int n = 0; n < 325; ++n) {
        float xv = (float)xs[n * 64 + e];
        re = fmaf(xv, fc[n], re);
        im = fmaf(xv, -fs[n], im);
      }
      xf_re[f * 64 + e] = re;
      xf_im[f * 64 + e] = im;
    }
  }
  __syncthreads();

  // ph3a: stage W^T [e][d] pad 66 (fp16)
  for (int i = tid; i < 4096; i += 256) {
    int dd = i >> 6, e = i & 63;
    wlds[e * 66 + dd] = (_Float16)Wq[i];
    wlds[4224 + e * 66 + dd] = (_Float16)Wk[i];
    wlds[8448 + e * 66 + dd] = (_Float16)Wv[i];
  }
  __syncthreads();

  // ph3b: qf/kf/vf into registers (8 modes per thread)
  const int d = tid & 63, fb = tid >> 6;
  float qre[8], qim[8], kre[8], kim[8], vre[8], vim[8];
  for (int it = 0; it < 8; ++it) {
    const int f = fb + (it << 2);
    float qr = 0, qi = 0, kr = 0, ki = 0, vr = 0, vi = 0;
    for (int e = 0; e < 64; ++e) {
      float xr = xf_re[f * 64 + e];
      float xi = xf_im[f * 64 + e];
      float wq = (float)wlds[e * 66 + d];
      float wk = (float)wlds[4224 + e * 66 + d];
      float wv = (float)wlds[8448 + e * 66 + d];
      qr = fmaf(xr, wq, qr); qi = fmaf(xi, wq, qi);
      kr = fmaf(xr, wk, kr); ki = fmaf(xi, wk, ki);
      vr = fmaf(xr, wv, vr); vi = fmaf(xi, wv, vi);
    }
    qre[it] = qr; qim[it] = qi; kre[it] = kr;
    kim[it] = ki; vre[it] = vr; vim[it] = vi;
  }
  __syncthreads();
  // ph3c: |qf|, SCALE*|kf|, vf, zero wbar
  const float inv_nq = ws[OFF_NORM + 0];
  const float inv_nk = ws[OFF_NORM + 1];
  for (int it = 0; it < 8; ++it) {
    const int f = fb + (it << 2);
    absq[f * 64 + d] = inv_nq * sqrtf(qre[it] * qre[it] + qim[it] * qim[it]);
    absk[f * 64 + d] = 0.25f * inv_nk * sqrtf(kre[it] * kre[it] + kim[it] * kim[it]);
    vf_re[f * 64 + d] = vre[it];
    vf_im[f * 64 + d] = vim[it];
    wbar[f * 64 + d] = 0.f;
  }
  __syncthreads();

  // ph4: wbar[j][d] = (1/32) sum_m softmax_j( absk[j][d] * A[m,j,d] )
  const float* wqa = ws + OFF_WQA;
  const int hd = d & 15;
  for (int r8 = 0; r8 < 8; ++r8) {
    const int m = (r8 << 2) + fb;
    float sv[32];
    const float aq = absq[m * 64 + d];
    float mx = -1e30f;
#pragma unroll
    for (int j = 0; j < 32; ++j) {
      float a = (j == 0) ? aq : wqa[(m * 31 + (j - 1)) * 16 + hd];
      float s = absk[j * 64 + d] * a;
      sv[j] = s;
      mx = fmaxf(mx, s);
    }
    float sum = 0.f;
#pragma unroll
    for (int j = 0; j < 32; ++j) {
      float ev = __expf(sv[j] - mx);
      sv[j] = ev;
      sum += ev;
    }
    const float sc = 0.03125f / sum;
#pragma unroll
    for (int j = 0; j < 32; ++j) atomicAdd(&wbar[j * 64 + d], sv[j] * sc);
  }
  __syncthreads();

  // ph5: of[j][d] = vf * wbar  -> global
  float2* OF = (float2*)(ws + OFF_OF);
  for (int i = tid; i < 2048; i += 256) {
    float w = wbar[i];
    OF[(size_t)bt * 2048 + i] = make_float2(vf_re[i] * w, vf_im[i] * w);
  }
}

// =======  K4: xc = x @ Wc^T, vt = x @ Wv_t^T  (64 rows / block)  =======
__global__ __launch_bounds__(256) void k_linear(const float* __restrict__ x,
                                                const float* __restrict__ Wvt,
                                                float* __restrict__ ws) {
  __shared__ __align__(16) float xlds[4096];
  __shared__ float wct[64 * 65];
  __shared__ float wvt[64 * 65];
  const int tid = threadIdx.x;
  const size_t base = (size_t)blockIdx.x * 64;  // 1950 blocks * 64 = 124800 rows
  {
    const float4* src = (const float4*)(x + base * 64);
    float4* dst = (float4*)xlds;
    for (int i = tid; i < 1024; i += 256) dst[i] = src[i];
  }
  for (int i = tid; i < 4096; i += 256) {
    int o = i >> 6, e = i & 63;
    wct[o * 65 + e] = ws[OFF_WC + i];
    wvt[o * 65 + e] = Wvt[i];
  }
  __syncthreads();
  const int c = tid & 63, rg = tid >> 6;
  for (int k = 0; k < 16; ++k) {
    const int r = rg * 16 + k;
    float a1 = 0.f, a2 = 0.f;
    for (int e = 0; e < 64; ++e) {
      float xv = xlds[r * 64 + e];
      a1 = fmaf(xv, wct[c * 65 + e], a1);
      a2 = fmaf(xv, wvt[c * 65 + e], a2);
    }
    ws[OFF_XC + (base + r) * 64 + c] = a1;
    ws[OFF_VT + (base + r) * 64 + c] = a2;
  }
}

// =======  K5: alt[b,n',d] = sum_s (-1)^s vt[b, n'*12+s, d]  =======
__global__ __launch_bounds__(256) void k_alt(float* __restrict__ ws) {
  const int idx = blockIdx.x * 256 + threadIdx.x;
  if (idx >= 32 * 325 * 64) return;
  const int dd = idx & 63;
  const int n = (idx >> 6) % 325;
  const int b = idx / (64 * 325);
  const float* vt = ws + OFF_VT + ((size_t)b * 3900 + (size_t)n * 12) * 64 + dd;
  float s = 0.f, sign = 1.f;
  for (int k = 0; k < 12; ++k) {
    s += sign * vt[k * 64];
    sign = -sign;
  }
  ws[OFF_ALT + idx] = s;
}

// =======  K6: GCN agg + spatial irfft + temporal + bias -> out (fp32)  =======
__global__ __launch_bounds__(256) void k_final(const float* __restrict__ bmlp,
                                               float* __restrict__ ws,
                                               float* __restrict__ out) {
  __shared__ __align__(16) float atile[64 * 68];
  __shared__ __align__(16) float xtile[64 * 68];
  const int tid = threadIdx.x;
  const int bt = blockIdx.x / 6, nt = blockIdx.x % 6;
  const int b = bt / 12, t = bt % 12;
  const int n0 = nt * 64;
  const int ty = tid >> 4, tx = tid & 15;
  float acc[4][4] = {};
  for (int kc = 0; kc < 6; ++kc) {
    const int k0 = kc * 64;
    __syncthreads();
    for (int i = tid; i < 4096; i += 256) {
      const int r = i >> 6, cix = i & 63;
      const int n = n0 + r, k = k0 + cix;
      atile[r * 68 + cix] =
          (n < 325 && k < 325) ? ws[OFF_AN + (size_t)n * 325 + k] : 0.f;
      xtile[r * 68 + cix] =
          (k0 + r < 325) ? ws[OFF_XC + ((size_t)bt * 325 + k0 + r) * 64 + cix] : 0.f;
    }
    __syncthreads();
    for (int kk = 0; kk < 64; ++kk) {
      float av[4], xv[4];
#pragma unroll
      for (int i2 = 0; i2 < 4; ++i2) av[i2] = atile[(ty * 4 + i2) * 68 + kk];
#pragma unroll
      for (int j2 = 0; j2 < 4; ++j2) xv[j2] = xtile[kk * 68 + tx * 4 + j2];
#pragma unroll
      for (int i2 = 0; i2 < 4; ++i2)
#pragma unroll
        for (int j2 = 0; j2 < 4; ++j2)
          acc[i2][j2] = fmaf(av[i2], xv[j2], acc[i2][j2]);
    }
  }
  __syncthreads();
  // stage of-spectrum + inverse twiddles
  float2* ofs = (float2*)atile;
  const float2* OF = (const float2*)(ws + OFF_OF);
  for (int i = tid; i < 2048; i += 256) ofs[i] = OF[(size_t)bt * 2048 + i];
  float* itc = xtile;
  float* its = xtile + 2048;
  for (int i = tid; i < 2048; i += 256) {
    const int j = i >> 6, nl = i & 63;
    const int n = n0 + nl;
    itc[i] = (n < 325) ? ws[OFF_ICOS + j * 325 + n] : 0.f;
    its[i] = (n < 325) ? ws[OFF_ISIN + j * 325 + n] : 0.f;
  }
  __syncthreads();
  float ysp[4][4] = {};
  for (int jm = 0; jm < 32; ++jm) {
    float ore[4], oim[4], tcv[4], tsv[4];
#pragma unroll
    for (int j2 = 0; j2 < 4; ++j2) {
      float2 o = ofs[jm * 64 + tx * 4 + j2];
      ore[j2] = o.x;
      oim[j2] = o.y;
    }
#pragma unroll
    for (int i2 = 0; i2 < 4; ++i2) {
      tcv[i2] = itc[jm * 64 + ty * 4 + i2];
      tsv[i2] = its[jm * 64 + ty * 4 + i2];
    }
#pragma unroll
    for (int i2 = 0; i2 < 4; ++i2)
#pragma unroll
      for (int j2 = 0; j2 < 4; ++j2)
        ysp[i2][j2] += ore[j2] * tcv[i2] - oim[j2] * tsv[i2];
  }
  const float sgn = (t & 1) ? -1.f : 1.f;
  float bcv[4];
#pragma unroll
  for (int j2 = 0; j2 < 4; ++j2) bcv[j2] = bmlp[tx * 4 + j2];
#pragma unroll
  for (int i2 = 0; i2 < 4; ++i2) {
    const int n = n0 + ty * 4 + i2;
    if (n >= 325) continue;
#pragma unroll
    for (int j2 = 0; j2 < 4; ++j2) {
      const int dd = tx * 4 + j2;
      float v = ws[OFF_VT + ((size_t)b * 3900 + (size_t)n * 12 + t) * 64 + dd];
      float al = ws[OFF_ALT + ((size_t)b * 325 + n) * 64 + dd];
      float te = (v - sgn * al * (1.f / 12.f)) * (1.f / 6.f);
      float r = acc[i2][j2] + bcv[j2] + ysp[i2][j2] + te;
      out[((size_t)bt * 325 + n) * 64 + dd] = r;
    }
  }
}

extern "C" void kernel_launch(void* const* d_in, const int* in_sizes, int n_in,
                              void* d_out, int out_size, void* d_ws, size_t ws_size,
                              hipStream_t stream) {
  const float* x = (const float*)d_in[0];
  const float* adj = (const float*)d_in[1];
  const float* Wq_g = (const float*)d_in[2];
  const float* Wk_g = (const float*)d_in[3];
  const float* Wv_g = (const float*)d_in[4];
  // d_in[5], d_in[6] (Wq_t, Wk_t), d_in[12] (weights_Q_t), d_in[14] (t_modes):
  // dead code — temporal softmax axis == mean axis => out = vf/6.
  const float* Wv_t = (const float*)d_in[7];
  const float* Wfc1 = (const float*)d_in[8];
  const float* Wmlp = (const float*)d_in[9];
  const float* bmlp = (const float*)d_in[10];
  const float* wQ = (const float*)d_in[11];
  const int* sp_modes = (const int*)d_in[13];
  float* ws = (float*)d_ws;
  float* out = (float*)d_out;

  (void)in_sizes; (void)n_in; (void)out_size; (void)ws_size;

  hipMemsetAsync(ws + OFF_G, 0, 4096 * sizeof(float), stream);
  k_gram<<<256, 256, 0, stream>>>(x, ws);
  k_prep<<<367, 256, 0, stream>>>(adj, Wq_g, Wk_g, Wmlp, Wfc1, wQ, sp_modes, ws);
  k_spatial<<<384, 256, 0, stream>>>(x, Wq_g, Wk_g, Wv_g, ws);
  k_linear<<<1950, 256, 0, stream>>>(x, Wv_t, ws);
  k_alt<<<2600, 256, 0, stream>>>(ws);
  k_final<<<2304, 256, 0, stream>>>(bmlp, ws, out);
}

// Round 3
// 586.887 us; speedup vs baseline: 1.3151x; 1.3151x over previous
//
#include <hip/hip_runtime.h>

// Problem: B=32,T=12,N=325,D=64,H=4,HD=16,M_SP=32,M_T=6, SCALE=0.25
// Inputs fp32 (+ int32 mode lists); output fp32.
//
// Key identities used:
//  * temporal branch: softmax axis == mean axis  =>  out = vf/6. Whole branch is
//    v=x@Wv_t^T (fake (n',t') reshape r = n'*12+t'), drop Nyquist of 12-pt rfft, /6:
//    te[t'] = (v[t'] - (-1)^{t'} * (sum_s (-1)^s v[s]) / 12) / 6
//  * rfft over n commutes with channel linear => one DFT of x, then 64x64 matmuls.
//  * ||x@W^T||_F^2 = sum_{e,e'} (W^T W)[e,e'] * G[e,e'],  G = sum_rows x x^T.
//  * GCN: Wc = W_mlp @ W_fc1 folded; out = A_rownorm @ (x @ Wc^T) + b.
//
// R2: spatial branch rewritten as two fused register-tiled GEMMs per bt
//     (DFT 64x64x325, then projection 64x192x64) + register-accumulated softmax.
//     Twiddles stored n-major (Tt[325][64]: cols 0..31=cos, 32..63=-sin).

typedef unsigned short u16;

// ---- workspace layout (float offsets) ----
constexpr size_t OFF_G    = 0;          // 4096   Gram (memset each launch, atomic-accumulated)
constexpr size_t OFF_NORM = 4096;       // 16     [0]=1/||q_s||, [1]=1/||k_s||
constexpr size_t OFF_WC   = 4112;       // 4096   Wc = Wmlp@Wfc1
constexpr size_t OFF_WQA  = 8208;       // 15872  |weights_Q|
constexpr size_t OFF_AN   = 24080;      // 105625 row-normalized adj
constexpr size_t OFF_TT   = 129712;     // 20800  Tt[n][64]: [0:32)=cos(2pi f_j n/325), [32:64)=-sin
constexpr size_t OFF_ICOS = 150512;     // 10400  wgt_j/325 * cos
constexpr size_t OFF_ISIN = 160912;     // 10400
constexpr size_t OFF_OF   = 171312;     // 1572864  spatial out-spectrum [bt][j][d] float2
constexpr size_t OFF_XC   = 1744176;    // 7987200  x @ Wc^T
constexpr size_t OFF_VT   = 9731376;    // 7987200  x @ Wv_t^T
constexpr size_t OFF_ALT  = 17718576;   // 665600   alternating sums per fake-time group
// total = 18,384,176 floats = 73.5 MB

// =====================  K1: Gram matrix G = sum_rows x x^T  =====================
__global__ __launch_bounds__(256) void k_gram(const float* __restrict__ x,
                                              float* __restrict__ ws) {
  __shared__ __align__(16) float xs[2048];   // [32 rows][64]
  const int tid = threadIdx.x;
  const int e0 = (tid >> 4) << 2;
  const int f0 = (tid & 15) << 2;
  float acc[4][4] = {};
  const int ROWS = 124800;  // B*T*N
  for (int r0 = blockIdx.x * 32; r0 < ROWS; r0 += gridDim.x * 32) {
    const float4* src = (const float4*)(x + (size_t)r0 * 64);
    float4* dst = (float4*)xs;
    for (int i = tid; i < 512; i += 256) dst[i] = src[i];
    __syncthreads();
    for (int rr = 0; rr < 32; ++rr) {
      float a[4], b[4];
#pragma unroll
      for (int i = 0; i < 4; ++i) a[i] = xs[rr * 64 + e0 + i];
#pragma unroll
      for (int j = 0; j < 4; ++j) b[j] = xs[rr * 64 + f0 + j];
#pragma unroll
      for (int i = 0; i < 4; ++i)
#pragma unroll
        for (int j = 0; j < 4; ++j) acc[i][j] = fmaf(a[i], b[j], acc[i][j]);
    }
    __syncthreads();
  }
#pragma unroll
  for (int i = 0; i < 4; ++i)
#pragma unroll
    for (int j = 0; j < 4; ++j)
      atomicAdd(&ws[OFF_G + (size_t)(e0 + i) * 64 + f0 + j], acc[i][j]);
}

// ===========  K2: norms, Wc, |wQ|, adj row-norm, twiddle tables  ===========
__global__ __launch_bounds__(256) void k_prep(const float* __restrict__ adj,
                                              const float* __restrict__ Wq,
                                              const float* __restrict__ Wk,
                                              const float* __restrict__ Wmlp,
                                              const float* __restrict__ Wfc1,
                                              const float* __restrict__ wQ,
                                              const int* __restrict__ sp_modes,
                                              float* __restrict__ ws) {
  __shared__ float ldsw[2 * 64 * 65];
  __shared__ float partial[4];
  __shared__ float red[256];
  const int tid = threadIdx.x;
  const int blk = blockIdx.x;
  if (blk == 0) {
    // ||q||^2 = sum_d Wq[d,:] G Wq[d,:]^T  (same for k); 4 waves: (q lo/hi e, k lo/hi e)
    for (int i = tid; i < 4096; i += 256) {
      int dd = i >> 6, e = i & 63;
      ldsw[dd * 65 + e] = Wq[i];
      ldsw[4160 + dd * 65 + e] = Wk[i];
    }
    __syncthreads();
    const int wave = tid >> 6, lane = tid & 63;
    const float* Wl = ldsw + ((wave >= 2) ? 4160 : 0);
    const int e0 = (wave & 1) * 32;
    float s = 0.f;
    for (int e = e0; e < e0 + 32; ++e) {
      const float* Gr = ws + OFF_G + (size_t)e * 64;
      float t = 0.f;
      for (int e2 = 0; e2 < 64; ++e2) t = fmaf(Gr[e2], Wl[lane * 65 + e2], t);
      s += Wl[lane * 65 + e] * t;
    }
    for (int off = 32; off > 0; off >>= 1) s += __shfl_down(s, off);
    if (lane == 0) partial[wave] = s;
    __syncthreads();
    if (tid == 0) {
      ws[OFF_NORM + 0] = rsqrtf(partial[0] + partial[1]);
      ws[OFF_NORM + 1] = rsqrtf(partial[2] + partial[3]);
    }
  } else if (blk == 1) {
    for (int o = tid; o < 4096; o += 256) {
      int g = o >> 6, dd = o & 63;
      float s = 0.f;
      for (int e = 0; e < 64; ++e)
        s = fmaf(Wmlp[g * 64 + e], Wfc1[e * 64 + dd], s);
      ws[OFF_WC + o] = s;
    }
  } else if (blk < 10) {
    for (int i = (blk - 2) * 256 + tid; i < 15872; i += 2048)
      ws[OFF_WQA + i] = fabsf(wQ[i]);
  } else if (blk < 335) {
    const int n = blk - 10;
    float p = 0.f;
    for (int k = tid; k < 325; k += 256) p += adj[n * 325 + k];
    red[tid] = p;
    __syncthreads();
    for (int s2 = 128; s2 > 0; s2 >>= 1) {
      if (tid < s2) red[tid] += red[tid + s2];
      __syncthreads();
    }
    const float inv = 1.f / red[0];
    for (int k = tid; k < 325; k += 256)
      ws[OFF_AN + (size_t)n * 325 + k] = adj[n * 325 + k] * inv;
  } else {
    const int j = blk - 335;  // < 32
    const int f = sp_modes[j];
    const float wgt = (f == 0) ? 1.f : 2.f;
    for (int n = tid; n < 325; n += 256) {
      int mm = (f * n) % 325;                 // exact range reduction
      float th = 6.283185307179586f * (float)mm * (1.f / 325.f);
      float c = cosf(th), s = sinf(th);
      ws[OFF_TT + (size_t)n * 64 + j] = c;
      ws[OFF_TT + (size_t)n * 64 + 32 + j] = -s;
      ws[OFF_ICOS + j * 325 + n] = wgt * (1.f / 325.f) * c;
      ws[OFF_ISIN + j * 325 + n] = wgt * (1.f / 325.f) * s;
    }
  }
}

// =======  K3: fused spatial branch per bt, register-tiled GEMMs  =======
// Phase A: C[64][64] = Tmat[64][325] @ x_bt[325][64]   (rows 0..31 re, 32..63 im)
// Phase B: out2[64][192] = C @ [Wq|Wk|Wv]^T             (cols grouped per matrix)
// Phase C: |q|,|k| via squared-sum atomics; softmax w/ register accumulation; of.
__global__ __launch_bounds__(256) void k_spatial2(const float* __restrict__ x,
                                                  const float* __restrict__ Wq,
                                                  const float* __restrict__ Wk,
                                                  const float* __restrict__ Wv,
                                                  float* __restrict__ ws) {
  __shared__ __align__(16) float smem[10880];   // 43,520 B
  const int tid = threadIdx.x;
  const int bt = blockIdx.x;
  const int tx = tid & 15, ty = tid >> 4;

  // ---------------- Phase A: DFT GEMM, 4x4 per thread ----------------
  float* Tt_tile = smem;          // [65][68]
  float* X_tile  = smem + 4420;   // [65][68]
  const float* Tt = ws + OFF_TT;  // [325][64]
  const float* xb = x + (size_t)bt * 20800;
  float acc[4][4] = {};
  for (int kc = 0; kc < 5; ++kc) {
    const int k0 = kc * 65;
    __syncthreads();
    for (int i = tid; i < 1040; i += 256) {
      const int r = i >> 4, cq = i & 15;
      ((float4*)(Tt_tile + r * 68))[cq] = ((const float4*)(Tt + (size_t)(k0 + r) * 64))[cq];
      ((float4*)(X_tile + r * 68))[cq]  = ((const float4*)(xb + (size_t)(k0 + r) * 64))[cq];
    }
    __syncthreads();
    for (int kk = 0; kk < 65; ++kk) {
      float av[4], bv[4];
      *(float4*)av = *(const float4*)(Tt_tile + kk * 68 + ty * 4);
      *(float4*)bv = *(const float4*)(X_tile + kk * 68 + tx * 4);
#pragma unroll
      for (int i = 0; i < 4; ++i)
#pragma unroll
        for (int j = 0; j < 4; ++j) acc[i][j] = fmaf(av[i], bv[j], acc[i][j]);
    }
  }
  __syncthreads();
  // write At[e][r] = C[r][e]  (transposed, for contiguous b128 reads in phase B)
  float* At = smem;               // [64][68]
#pragma unroll
  for (int i = 0; i < 4; ++i)
#pragma unroll
    for (int j = 0; j < 4; ++j)
      At[(tx * 4 + j) * 68 + (ty * 4 + i)] = acc[i][j];

  // ---------------- Phase B: projection GEMM, 4x12 per thread ----------------
  float* Wt3c = smem + 4420;      // [32][196]: cols 0..63 Wq^T, 64..127 Wk^T, 128..191 Wv^T
  float acc2[4][12] = {};
  for (int ec = 0; ec < 2; ++ec) {
    __syncthreads();
    for (int i = tid; i < 6144; i += 256) {
      const int c = i >> 5, el = i & 31;
      const int mat = c >> 6, dd = c & 63;
      const float* Wm = (mat == 0) ? Wq : (mat == 1) ? Wk : Wv;
      Wt3c[el * 196 + c] = Wm[dd * 64 + ec * 32 + el];
    }
    __syncthreads();
    for (int kk = 0; kk < 32; ++kk) {
      float av[4], bv[12];
      *(float4*)av = *(const float4*)(At + (ec * 32 + kk) * 68 + ty * 4);
      *(float4*)(bv + 0) = *(const float4*)(Wt3c + kk * 196 + tx * 4);
      *(float4*)(bv + 4) = *(const float4*)(Wt3c + kk * 196 + 64 + tx * 4);
      *(float4*)(bv + 8) = *(const float4*)(Wt3c + kk * 196 + 128 + tx * 4);
#pragma unroll
      for (int i = 0; i < 4; ++i)
#pragma unroll
        for (int c2 = 0; c2 < 12; ++c2) acc2[i][c2] = fmaf(av[i], bv[c2], acc2[i][c2]);
    }
  }
  __syncthreads();

  // ---------------- Phase C: magnitudes + softmax + of ----------------
  float* sq_q = smem;             // [32][64]
  float* sq_k = smem + 2048;      // [32][64] -> becomes absk in place
  float* vfre = smem + 4096;      // [32][64]
  float* vfim = smem + 6144;      // [32][64]
  float* wbar = smem + 8192;      // [32][64]
  for (int i = tid; i < 2048; i += 256) {
    sq_q[i] = 0.f; sq_k[i] = 0.f; wbar[i] = 0.f;
  }
  __syncthreads();
  {
    const int rbase = ty * 4;
    const bool is_re = rbase < 32;
    const int f0 = is_re ? rbase : rbase - 32;
#pragma unroll
    for (int i = 0; i < 4; ++i) {
      const int f = f0 + i;
#pragma unroll
      for (int j = 0; j < 4; ++j) {
        const int dd = tx * 4 + j;
        const float qv = acc2[i][j], kv = acc2[i][4 + j], vv = acc2[i][8 + j];
        atomicAdd(&sq_q[f * 64 + dd], qv * qv);
        atomicAdd(&sq_k[f * 64 + dd], kv * kv);
        if (is_re) vfre[f * 64 + dd] = vv; else vfim[f * 64 + dd] = vv;
      }
    }
  }
  __syncthreads();
  const float inv_nq = ws[OFF_NORM + 0];
  const float inv_nk = ws[OFF_NORM + 1];
  for (int i = tid; i < 2048; i += 256)
    sq_k[i] = 0.25f * inv_nk * sqrtf(sq_k[i]);
  __syncthreads();
  {
    const int d = tid & 63, fb = tid >> 6, hd = d & 15;
    const float* wqa = ws + OFF_WQA;
    float wacc[32];
#pragma unroll
    for (int j = 0; j < 32; ++j) wacc[j] = 0.f;
    for (int r8 = 0; r8 < 8; ++r8) {
      const int m = fb + (r8 << 2);
      const float aq = inv_nq * sqrtf(sq_q[m * 64 + d]);
      float sv[32];
      float mx = -1e30f;
#pragma unroll
      for (int j = 0; j < 32; ++j) {
        const float a = (j == 0) ? aq : wqa[(m * 31 + (j - 1)) * 16 + hd];
        const float s = sq_k[j * 64 + d] * a;
        sv[j] = s;
        mx = fmaxf(mx, s);
      }
      float sum = 0.f;
#pragma unroll
      for (int j = 0; j < 32; ++j) {
        const float ev = __expf(sv[j] - mx);
        sv[j] = ev;
        sum += ev;
      }
      const float sc = 0.03125f / sum;
#pragma unroll
      for (int j = 0; j < 32; ++j) wacc[j] += sv[j] * sc;
    }
#pragma unroll
    for (int j = 0; j < 32; ++j) atomicAdd(&wbar[j * 64 + d], wacc[j]);
  }
  __syncthreads();
  float2* OF = (float2*)(ws + OFF_OF);
  for (int i = tid; i < 2048; i += 256) {
    const float w = wbar[i];
    OF[(size_t)bt * 2048 + i] = make_float2(vfre[i] * w, vfim[i] * w);
  }
}

// =======  K4: xc = x @ Wc^T, vt = x @ Wv_t^T  (64 rows / block)  =======
__global__ __launch_bounds__(256) void k_linear(const float* __restrict__ x,
                                                const float* __restrict__ Wvt,
                                                float* __restrict__ ws) {
  __shared__ __align__(16) float xlds[4096];
  __shared__ float wct[64 * 65];
  __shared__ float wvt[64 * 65];
  const int tid = threadIdx.x;
  const size_t base = (size_t)blockIdx.x * 64;  // 1950 blocks * 64 = 124800 rows
  {
    const float4* src = (const float4*)(x + base * 64);
    float4* dst = (float4*)xlds;
    for (int i = tid; i < 1024; i += 256) dst[i] = src[i];
  }
  for (int i = tid; i < 4096; i += 256) {
    int o = i >> 6, e = i & 63;
    wct[o * 65 + e] = ws[OFF_WC + i];
    wvt[o * 65 + e] = Wvt[i];
  }
  __syncthreads();
  const int c = tid & 63, rg = tid >> 6;
  for (int k = 0; k < 16; ++k) {
    const int r = rg * 16 + k;
    float a1 = 0.f, a2 = 0.f;
    for (int e = 0; e < 64; ++e) {
      float xv = xlds[r * 64 + e];
      a1 = fmaf(xv, wct[c * 65 + e], a1);
      a2 = fmaf(xv, wvt[c * 65 + e], a2);
    }
    ws[OFF_XC + (base + r) * 64 + c] = a1;
    ws[OFF_VT + (base + r) * 64 + c] = a2;
  }
}

// =======  K5: alt[b,n',d] = sum_s (-1)^s vt[b, n'*12+s, d]  =======
__global__ __launch_bounds__(256) void k_alt(float* __restrict__ ws) {
  const int idx = blockIdx.x * 256 + threadIdx.x;
  if (idx >= 32 * 325 * 64) return;
  const int dd = idx & 63;
  const int n = (idx >> 6) % 325;
  const int b = idx / (64 * 325);
  const float* vt = ws + OFF_VT + ((size_t)b * 3900 + (size_t)n * 12) * 64 + dd;
  float s = 0.f, sign = 1.f;
  for (int k = 0; k < 12; ++k) {
    s += sign * vt[k * 64];
    sign = -sign;
  }
  ws[OFF_ALT + idx] = s;
}

// =======  K6: GCN agg + spatial irfft + temporal + bias -> out (fp32)  =======
__global__ __launch_bounds__(256) void k_final(const float* __restrict__ bmlp,
                                               float* __restrict__ ws,
                                               float* __restrict__ out) {
  __shared__ __align__(16) float atile[64 * 68];
  __shared__ __align__(16) float xtile[64 * 68];
  const int tid = threadIdx.x;
  const int bt = blockIdx.x / 6, nt = blockIdx.x % 6;
  const int b = bt / 12, t = bt % 12;
  const int n0 = nt * 64;
  const int ty = tid >> 4, tx = tid & 15;
  float acc[4][4] = {};
  for (int kc = 0; kc < 6; ++kc) {
    const int k0 = kc * 64;
    __syncthreads();
    for (int i = tid; i < 4096; i += 256) {
      const int r = i >> 6, cix = i & 63;
      const int n = n0 + r, k = k0 + cix;
      atile[r * 68 + cix] =
          (n < 325 && k < 325) ? ws[OFF_AN + (size_t)n * 325 + k] : 0.f;
      xtile[r * 68 + cix] =
          (k0 + r < 325) ? ws[OFF_XC + ((size_t)bt * 325 + k0 + r) * 64 + cix] : 0.f;
    }
    __syncthreads();
    for (int kk = 0; kk < 64; ++kk) {
      float av[4], xv[4];
#pragma unroll
      for (int i2 = 0; i2 < 4; ++i2) av[i2] = atile[(ty * 4 + i2) * 68 + kk];
#pragma unroll
      for (int j2 = 0; j2 < 4; ++j2) xv[j2] = xtile[kk * 68 + tx * 4 + j2];
#pragma unroll
      for (int i2 = 0; i2 < 4; ++i2)
#pragma unroll
        for (int j2 = 0; j2 < 4; ++j2)
          acc[i2][j2] = fmaf(av[i2], xv[j2], acc[i2][j2]);
    }
  }
  __syncthreads();
  // stage of-spectrum + inverse twiddles
  float2* ofs = (float2*)atile;
  const float2* OF = (const float2*)(ws + OFF_OF);
  for (int i = tid; i < 2048; i += 256) ofs[i] = OF[(size_t)bt * 2048 + i];
  float* itc = xtile;
  float* its = xtile + 2048;
  for (int i = tid; i < 2048; i += 256) {
    const int j = i >> 6, nl = i & 63;
    const int n = n0 + nl;
    itc[i] = (n < 325) ? ws[OFF_ICOS + j * 325 + n] : 0.f;
    its[i] = (n < 325) ? ws[OFF_ISIN + j * 325 + n] : 0.f;
  }
  __syncthreads();
  float ysp[4][4] = {};
  for (int jm = 0; jm < 32; ++jm) {
    float ore[4], oim[4], tcv[4], tsv[4];
#pragma unroll
    for (int j2 = 0; j2 < 4; ++j2) {
      float2 o = ofs[jm * 64 + tx * 4 + j2];
      ore[j2] = o.x;
      oim[j2] = o.y;
    }
#pragma unroll
    for (int i2 = 0; i2 < 4; ++i2) {
      tcv[i2] = itc[jm * 64 + ty * 4 + i2];
      tsv[i2] = its[jm * 64 + ty * 4 + i2];
    }
#pragma unroll
    for (int i2 = 0; i2 < 4; ++i2)
#pragma unroll
      for (int j2 = 0; j2 < 4; ++j2)
        ysp[i2][j2] += ore[j2] * tcv[i2] - oim[j2] * tsv[i2];
  }
  const float sgn = (t & 1) ? -1.f : 1.f;
  float bcv[4];
#pragma unroll
  for (int j2 = 0; j2 < 4; ++j2) bcv[j2] = bmlp[tx * 4 + j2];
#pragma unroll
  for (int i2 = 0; i2 < 4; ++i2) {
    const int n = n0 + ty * 4 + i2;
    if (n >= 325) continue;
#pragma unroll
    for (int j2 = 0; j2 < 4; ++j2) {
      const int dd = tx * 4 + j2;
      float v = ws[OFF_VT + ((size_t)b * 3900 + (size_t)n * 12 + t) * 64 + dd];
      float al = ws[OFF_ALT + ((size_t)b * 325 + n) * 64 + dd];
      float te = (v - sgn * al * (1.f / 12.f)) * (1.f / 6.f);
      float r = acc[i2][j2] + bcv[j2] + ysp[i2][j2] + te;
      out[((size_t)bt * 325 + n) * 64 + dd] = r;
    }
  }
}

extern "C" void kernel_launch(void* const* d_in, const int* in_sizes, int n_in,
                              void* d_out, int out_size, void* d_ws, size_t ws_size,
                              hipStream_t stream) {
  const float* x = (const float*)d_in[0];
  const float* adj = (const float*)d_in[1];
  const float* Wq_g = (const float*)d_in[2];
  const float* Wk_g = (const float*)d_in[3];
  const float* Wv_g = (const float*)d_in[4];
  // d_in[5], d_in[6] (Wq_t, Wk_t), d_in[12] (weights_Q_t), d_in[14] (t_modes):
  // dead code — temporal softmax axis == mean axis => out = vf/6.
  const float* Wv_t = (const float*)d_in[7];
  const float* Wfc1 = (const float*)d_in[8];
  const float* Wmlp = (const float*)d_in[9];
  const float* bmlp = (const float*)d_in[10];
  const float* wQ = (const float*)d_in[11];
  const int* sp_modes = (const int*)d_in[13];
  float* ws = (float*)d_ws;
  float* out = (float*)d_out;

  (void)in_sizes; (void)n_in; (void)out_size; (void)ws_size;

  hipMemsetAsync(ws + OFF_G, 0, 4096 * sizeof(float), stream);
  k_gram<<<256, 256, 0, stream>>>(x, ws);
  k_prep<<<367, 256, 0, stream>>>(adj, Wq_g, Wk_g, Wmlp, Wfc1, wQ, sp_modes, ws);
  k_spatial2<<<384, 256, 0, stream>>>(x, Wq_g, Wk_g, Wv_g, ws);
  k_linear<<<1950, 256, 0, stream>>>(x, Wv_t, ws);
  k_alt<<<2600, 256, 0, stream>>>(ws);
  k_final<<<2304, 256, 0, stream>>>(bmlp, ws, out);
}

// Round 5
// 364.798 us; speedup vs baseline: 2.1157x; 1.6088x over previous
//
#include <hip/hip_runtime.h>

// Problem: B=32,T=12,N=325,D=64,H=4,HD=16,M_SP=32,M_T=6, SCALE=0.25
// Inputs fp32 (+ int32 mode lists); output fp32.
//
// Key identities used:
//  * temporal branch: softmax axis == mean axis  =>  out = vf/6. Whole branch is
//    v=x@Wv_t^T (fake (n',t') reshape r = n'*12+t'), drop Nyquist of 12-pt rfft, /6:
//    te[t'] = (v[t'] - (-1)^{t'} * (sum_s (-1)^s v[s]) / 12) / 6
//  * rfft over n commutes with channel linear => one DFT of x, then 64x64 matmuls.
//  * ||x@W^T||_F^2 = sum_{e,e'} (W^T W)[e,e'] * G[e,e'],  G = sum_rows x x^T.
//  * GCN: Wc = W_mlp @ W_fc1 folded; out = A_rownorm @ (x @ Wc^T) + b.
//
// R3: k_final -> MFMA (16x16x32 bf16).  C = AN@XC + T2@OF folded into one
//     13-chunk K loop per (bt, 128-row tile).
// R4 fix: k_linear XCT emit read xlds as [row][channel] but it is written
//     [channel][row] -> GCN input transposed (absmax 0.078). One-line fix.

typedef unsigned short u16;
typedef short short8 __attribute__((ext_vector_type(8)));
typedef float floatx4 __attribute__((ext_vector_type(4)));

__device__ __forceinline__ u16 f2bf(float f) {
  union { float fp; unsigned int u; } v; v.fp = f;
  unsigned int x = v.u;
  x += 0x7FFF + ((x >> 16) & 1);   // RNE
  return (u16)(x >> 16);
}

// ---- workspace layout (float offsets; u16 arrays count as size/2 floats) ----
constexpr size_t OFF_G    = 0;          // 4096    Gram (memset each launch)
constexpr size_t OFF_NORM = 4096;       // 16      [0]=1/||q||, [1]=1/||k||
constexpr size_t OFF_WC   = 4112;       // 4096    Wc = Wmlp@Wfc1
constexpr size_t OFF_WQA  = 8208;       // 15872   |weights_Q|
constexpr size_t OFF_ANB  = 24080;      // u16[325*352]   row-norm adj, bf16, col-pad 352
constexpr size_t OFF_TT   = 81280;      // f32 Tt[325][64]: [0:32)=cos, [32:64)=-sin
constexpr size_t OFF_T2   = 102080;     // u16[325*64]    irfft: [n][2j]=wc_j cos, [n][2j+1]=-wc_j sin
constexpr size_t OFF_OFT  = 112480;     // u16[384*64*64] spectrum [bt][d][2j|2j+1] (re,im)
constexpr size_t OFF_XCT  = 898912;     // u16[384*64*352] xc transposed [bt][d][n], n-pad 352
constexpr size_t OFF_VT   = 5224288;    // f32[124800*64]  x @ Wv_t^T
constexpr size_t OFF_ALT  = 13211488;   // f32[665600]     alternating sums
// total = 13,877,088 floats = 55.5 MB

// =====================  K1: Gram matrix G = sum_rows x x^T  =====================
__global__ __launch_bounds__(256) void k_gram(const float* __restrict__ x,
                                              float* __restrict__ ws) {
  __shared__ __align__(16) float xs[2048];   // [32 rows][64]
  const int tid = threadIdx.x;
  const int e0 = (tid >> 4) << 2;
  const int f0 = (tid & 15) << 2;
  float acc[4][4] = {};
  const int ROWS = 124800;  // B*T*N
  for (int r0 = blockIdx.x * 32; r0 < ROWS; r0 += gridDim.x * 32) {
    const float4* src = (const float4*)(x + (size_t)r0 * 64);
    float4* dst = (float4*)xs;
    for (int i = tid; i < 512; i += 256) dst[i] = src[i];
    __syncthreads();
    for (int rr = 0; rr < 32; ++rr) {
      float a[4], b[4];
#pragma unroll
      for (int i = 0; i < 4; ++i) a[i] = xs[rr * 64 + e0 + i];
#pragma unroll
      for (int j = 0; j < 4; ++j) b[j] = xs[rr * 64 + f0 + j];
#pragma unroll
      for (int i = 0; i < 4; ++i)
#pragma unroll
        for (int j = 0; j < 4; ++j) acc[i][j] = fmaf(a[i], b[j], acc[i][j]);
    }
    __syncthreads();
  }
#pragma unroll
  for (int i = 0; i < 4; ++i)
#pragma unroll
    for (int j = 0; j < 4; ++j)
      atomicAdd(&ws[OFF_G + (size_t)(e0 + i) * 64 + f0 + j], acc[i][j]);
}

// ===========  K2: norms, Wc, |wQ|, adj row-norm (bf16), twiddle tables  ===========
__global__ __launch_bounds__(256) void k_prep(const float* __restrict__ adj,
                                              const float* __restrict__ Wq,
                                              const float* __restrict__ Wk,
                                              const float* __restrict__ Wmlp,
                                              const float* __restrict__ Wfc1,
                                              const float* __restrict__ wQ,
                                              const int* __restrict__ sp_modes,
                                              float* __restrict__ ws) {
  __shared__ float ldsw[2 * 64 * 65];
  __shared__ float partial[4];
  __shared__ float red[256];
  const int tid = threadIdx.x;
  const int blk = blockIdx.x;
  if (blk == 0) {
    for (int i = tid; i < 4096; i += 256) {
      int dd = i >> 6, e = i & 63;
      ldsw[dd * 65 + e] = Wq[i];
      ldsw[4160 + dd * 65 + e] = Wk[i];
    }
    __syncthreads();
    const int wave = tid >> 6, lane = tid & 63;
    const float* Wl = ldsw + ((wave >= 2) ? 4160 : 0);
    const int e0 = (wave & 1) * 32;
    float s = 0.f;
    for (int e = e0; e < e0 + 32; ++e) {
      const float* Gr = ws + OFF_G + (size_t)e * 64;
      float t = 0.f;
      for (int e2 = 0; e2 < 64; ++e2) t = fmaf(Gr[e2], Wl[lane * 65 + e2], t);
      s += Wl[lane * 65 + e] * t;
    }
    for (int off = 32; off > 0; off >>= 1) s += __shfl_down(s, off);
    if (lane == 0) partial[wave] = s;
    __syncthreads();
    if (tid == 0) {
      ws[OFF_NORM + 0] = rsqrtf(partial[0] + partial[1]);
      ws[OFF_NORM + 1] = rsqrtf(partial[2] + partial[3]);
    }
  } else if (blk == 1) {
    for (int o = tid; o < 4096; o += 256) {
      int g = o >> 6, dd = o & 63;
      float s = 0.f;
      for (int e = 0; e < 64; ++e)
        s = fmaf(Wmlp[g * 64 + e], Wfc1[e * 64 + dd], s);
      ws[OFF_WC + o] = s;
    }
  } else if (blk < 10) {
    for (int i = (blk - 2) * 256 + tid; i < 15872; i += 2048)
      ws[OFF_WQA + i] = fabsf(wQ[i]);
  } else if (blk < 335) {
    const int n = blk - 10;
    float p = 0.f;
    for (int k = tid; k < 325; k += 256) p += adj[n * 325 + k];
    red[tid] = p;
    __syncthreads();
    for (int s2 = 128; s2 > 0; s2 >>= 1) {
      if (tid < s2) red[tid] += red[tid + s2];
      __syncthreads();
    }
    const float inv = 1.f / red[0];
    u16* ANB = (u16*)(ws + OFF_ANB);
    for (int k = tid; k < 352; k += 256)
      ANB[(size_t)n * 352 + k] = (k < 325) ? f2bf(adj[n * 325 + k] * inv) : (u16)0;
  } else {
    const int j = blk - 335;  // < 32
    const int f = sp_modes[j];
    const float wgt = (f == 0) ? 1.f : 2.f;
    u16* T2B = (u16*)(ws + OFF_T2);
    for (int n = tid; n < 325; n += 256) {
      int mm = (f * n) % 325;                 // exact range reduction
      float th = 6.283185307179586f * (float)mm * (1.f / 325.f);
      float c = cosf(th), s = sinf(th);
      ws[OFF_TT + (size_t)n * 64 + j] = c;
      ws[OFF_TT + (size_t)n * 64 + 32 + j] = -s;
      T2B[(size_t)n * 64 + 2 * j] = f2bf(wgt * (1.f / 325.f) * c);
      T2B[(size_t)n * 64 + 2 * j + 1] = f2bf(-wgt * (1.f / 325.f) * s);
    }
  }
}

// =======  K3: fused spatial branch per bt, register-tiled GEMMs  =======
__global__ __launch_bounds__(256) void k_spatial2(const float* __restrict__ x,
                                                  const float* __restrict__ Wq,
                                                  const float* __restrict__ Wk,
                                                  const float* __restrict__ Wv,
                                                  float* __restrict__ ws) {
  __shared__ __align__(16) float smem[10880];   // 43,520 B
  const int tid = threadIdx.x;
  const int bt = blockIdx.x;
  const int tx = tid & 15, ty = tid >> 4;

  // ---------------- Phase A: DFT GEMM, 4x4 per thread ----------------
  float* Tt_tile = smem;          // [65][68]
  float* X_tile  = smem + 4420;   // [65][68]
  const float* Tt = ws + OFF_TT;  // [325][64]
  const float* xb = x + (size_t)bt * 20800;
  float acc[4][4] = {};
  for (int kc = 0; kc < 5; ++kc) {
    const int k0 = kc * 65;
    __syncthreads();
    for (int i = tid; i < 1040; i += 256) {
      const int r = i >> 4, cq = i & 15;
      ((float4*)(Tt_tile + r * 68))[cq] = ((const float4*)(Tt + (size_t)(k0 + r) * 64))[cq];
      ((float4*)(X_tile + r * 68))[cq]  = ((const float4*)(xb + (size_t)(k0 + r) * 64))[cq];
    }
    __syncthreads();
    for (int kk = 0; kk < 65; ++kk) {
      float av[4], bv[4];
      *(float4*)av = *(const float4*)(Tt_tile + kk * 68 + ty * 4);
      *(float4*)bv = *(const float4*)(X_tile + kk * 68 + tx * 4);
#pragma unroll
      for (int i = 0; i < 4; ++i)
#pragma unroll
        for (int j = 0; j < 4; ++j) acc[i][j] = fmaf(av[i], bv[j], acc[i][j]);
    }
  }
  __syncthreads();
  float* At = smem;               // [64 e][68] = C^T
#pragma unroll
  for (int i = 0; i < 4; ++i)
#pragma unroll
    for (int j = 0; j < 4; ++j)
      At[(tx * 4 + j) * 68 + (ty * 4 + i)] = acc[i][j];

  // ---------------- Phase B: projection GEMM, 4x12 per thread ----------------
  float* Wt3c = smem + 4420;      // [32][196]
  float acc2[4][12] = {};
  for (int ec = 0; ec < 2; ++ec) {
    __syncthreads();
    for (int i = tid; i < 6144; i += 256) {
      const int c = i >> 5, el = i & 31;
      const int mat = c >> 6, dd = c & 63;
      const float* Wm = (mat == 0) ? Wq : (mat == 1) ? Wk : Wv;
      Wt3c[el * 196 + c] = Wm[dd * 64 + ec * 32 + el];
    }
    __syncthreads();
    for (int kk = 0; kk < 32; ++kk) {
      float av[4], bv[12];
      *(float4*)av = *(const float4*)(At + (ec * 32 + kk) * 68 + ty * 4);
      *(float4*)(bv + 0) = *(const float4*)(Wt3c + kk * 196 + tx * 4);
      *(float4*)(bv + 4) = *(const float4*)(Wt3c + kk * 196 + 64 + tx * 4);
      *(float4*)(bv + 8) = *(const float4*)(Wt3c + kk * 196 + 128 + tx * 4);
#pragma unroll
      for (int i = 0; i < 4; ++i)
#pragma unroll
        for (int c2 = 0; c2 < 12; ++c2) acc2[i][c2] = fmaf(av[i], bv[c2], acc2[i][c2]);
    }
  }
  __syncthreads();

  // ---------------- Phase C: magnitudes + softmax + OFT(bf16) ----------------
  float* sq_q = smem;             // [32][64]
  float* sq_k = smem + 2048;      // [32][64] -> absk*SCALE/||k||
  float* vfre = smem + 4096;
  float* vfim = smem + 6144;
  float* wbar = smem + 8192;
  for (int i = tid; i < 2048; i += 256) {
    sq_q[i] = 0.f; sq_k[i] = 0.f; wbar[i] = 0.f;
  }
  __syncthreads();
  {
    const int rbase = ty * 4;
    const bool is_re = rbase < 32;
    const int f0 = is_re ? rbase : rbase - 32;
#pragma unroll
    for (int i = 0; i < 4; ++i) {
      const int f = f0 + i;
#pragma unroll
      for (int j = 0; j < 4; ++j) {
        const int dd = tx * 4 + j;
        const float qv = acc2[i][j], kv = acc2[i][4 + j], vv = acc2[i][8 + j];
        atomicAdd(&sq_q[f * 64 + dd], qv * qv);
        atomicAdd(&sq_k[f * 64 + dd], kv * kv);
        if (is_re) vfre[f * 64 + dd] = vv; else vfim[f * 64 + dd] = vv;
      }
    }
  }
  __syncthreads();
  const float inv_nq = ws[OFF_NORM + 0];
  const float inv_nk = ws[OFF_NORM + 1];
  for (int i = tid; i < 2048; i += 256)
    sq_k[i] = 0.25f * inv_nk * sqrtf(sq_k[i]);
  __syncthreads();
  {
    const int d = tid & 63, fb = tid >> 6, hd = d & 15;
    const float* wqa = ws + OFF_WQA;
    float wacc[32];
#pragma unroll
    for (int j = 0; j < 32; ++j) wacc[j] = 0.f;
    for (int r8 = 0; r8 < 8; ++r8) {
      const int m = fb + (r8 << 2);
      const float aq = inv_nq * sqrtf(sq_q[m * 64 + d]);
      float sv[32];
      float mx = -1e30f;
#pragma unroll
      for (int j = 0; j < 32; ++j) {
        const float a = (j == 0) ? aq : wqa[(m * 31 + (j - 1)) * 16 + hd];
        const float s = sq_k[j * 64 + d] * a;
        sv[j] = s;
        mx = fmaxf(mx, s);
      }
      float sum = 0.f;
#pragma unroll
      for (int j = 0; j < 32; ++j) {
        const float ev = __expf(sv[j] - mx);
        sv[j] = ev;
        sum += ev;
      }
      const float sc = 0.03125f / sum;
#pragma unroll
      for (int j = 0; j < 32; ++j) wacc[j] += sv[j] * sc;
    }
#pragma unroll
    for (int j = 0; j < 32; ++j) atomicAdd(&wbar[j * 64 + d], wacc[j]);
  }
  __syncthreads();
  // OFT[bt][d][2j|2j+1] packed bf16, coalesced uint writes
  unsigned int* OFTu = (unsigned int*)(ws + OFF_OFT) + (size_t)bt * 2048;
  for (int i2 = tid; i2 < 2048; i2 += 256) {
    const int d = i2 >> 5, j = i2 & 31;
    const float w = wbar[j * 64 + d];
    const unsigned int lo = f2bf(vfre[j * 64 + d] * w);
    const unsigned int hi = f2bf(vfim[j * 64 + d] * w);
    OFTu[i2] = lo | (hi << 16);
  }
}

// =======  K4: xc = x @ Wc^T (-> XCT bf16 transposed), vt = x @ Wv_t^T (f32)  =======
__global__ __launch_bounds__(256) void k_linear(const float* __restrict__ x,
                                                const float* __restrict__ Wvt,
                                                float* __restrict__ ws) {
  __shared__ __align__(16) float xlds[4160];   // [64][65]: x staged [row][64], then xc^T [chan][row] pad-65
  __shared__ float wct[64 * 65];
  __shared__ float wvt[64 * 65];
  const int tid = threadIdx.x;
  const size_t base = (size_t)blockIdx.x * 64;  // 1950 blocks * 64 rows
  {
    const float4* src = (const float4*)(x + base * 64);
    for (int i = tid; i < 1024; i += 256)
      ((float4*)xlds)[i] = src[i];
  }
  for (int i = tid; i < 4096; i += 256) {
    int o = i >> 6, e = i & 63;
    wct[o * 65 + e] = ws[OFF_WC + i];
    wvt[o * 65 + e] = Wvt[i];
  }
  __syncthreads();
  const int c = tid & 63, rg = tid >> 6;
  float a1v[16];
  for (int k = 0; k < 16; ++k) {
    const int r = rg * 16 + k;
    float a1 = 0.f, a2 = 0.f;
    for (int e = 0; e < 64; ++e) {
      float xv = xlds[r * 64 + e];
      a1 = fmaf(xv, wct[c * 65 + e], a1);
      a2 = fmaf(xv, wvt[c * 65 + e], a2);
    }
    a1v[k] = a1;
    ws[OFF_VT + (base + r) * 64 + c] = a2;
  }
  __syncthreads();   // done reading xlds
  for (int k = 0; k < 16; ++k)
    xlds[c * 65 + rg * 16 + k] = a1v[k];   // [channel c][row r] pad-65
  __syncthreads();
  u16* XCT = (u16*)(ws + OFF_XCT);
  for (int i = tid; i < 4096; i += 256) {
    const int d = i >> 6, idx = i & 63;     // d = channel, idx = local row
    const unsigned int r = (unsigned int)(base + idx);
    const unsigned int bt = r / 325u;
    const unsigned int n = r - bt * 325u;
    // R4 fix: xlds is [channel][row] -> read xlds[d*65 + idx] (was idx*65+d, transposed)
    XCT[(size_t)bt * 22528 + (size_t)d * 352 + n] = f2bf(xlds[d * 65 + idx]);
  }
}

// =======  K5: alt[b,n',d] = sum_s (-1)^s vt[b, n'*12+s, d]  =======
__global__ __launch_bounds__(256) void k_alt(float* __restrict__ ws) {
  const int idx = blockIdx.x * 256 + threadIdx.x;
  if (idx >= 32 * 325 * 64) return;
  const int dd = idx & 63;
  const int n = (idx >> 6) % 325;
  const int b = idx / (64 * 325);
  const float* vt = ws + OFF_VT + ((size_t)b * 3900 + (size_t)n * 12) * 64 + dd;
  float s = 0.f, sign = 1.f;
  for (int k = 0; k < 12; ++k) {
    s += sign * vt[k * 64];
    sign = -sign;
  }
  ws[OFF_ALT + idx] = s;
}

// =======  K6: MFMA — C = AN@XCT + T2@OFT, + temporal + bias -> out  =======
// grid = 384 bt * 3 m-chunks; block 256 = 4 waves; wave does 32x64 of C.
__global__ __launch_bounds__(256) void k_final2(const float* __restrict__ bmlp,
                                                float* __restrict__ ws,
                                                float* __restrict__ out) {
  __shared__ __align__(16) u16 Atile[128 * 32];   // 8 KB
  __shared__ __align__(16) u16 Btile[64 * 32];    // 4 KB
  const int tid = threadIdx.x;
  const int bt = blockIdx.x / 3, mc = blockIdx.x % 3;
  const int m0 = mc * 128;
  const int wave = tid >> 6, lane = tid & 63;
  const int quad = lane >> 4, lc = lane & 15;

  const u16* ANB = (const u16*)(ws + OFF_ANB);
  const u16* T2B = (const u16*)(ws + OFF_T2);
  const u16* XCT = (const u16*)(ws + OFF_XCT) + (size_t)bt * 22528;
  const u16* OFT = (const u16*)(ws + OFF_OFT) + (size_t)bt * 4096;

  floatx4 acc[2][4] = {};

  for (int c13 = 0; c13 < 13; ++c13) {
    const bool gcn = (c13 < 11);
    const u16* Asrc = gcn ? ANB : T2B;
    const int astr = gcn ? 352 : 64;
    const int acol = gcn ? c13 * 32 : (c13 - 11) * 32;
    const u16* Bsrc = gcn ? XCT : OFT;
    const int bstr = gcn ? 352 : 64;
    __syncthreads();
    // stage A: 128x32 bf16 (2x uint4 per thread), rows >=325 zero
    for (int i = tid; i < 512; i += 256) {
      const int row = i >> 2, c8 = (i & 3) * 8;
      const int gr = m0 + row;
      uint4 v = make_uint4(0, 0, 0, 0);
      if (gr < 325)
        v = *(const uint4*)(Asrc + (size_t)gr * astr + acol + c8);
      *(uint4*)&Atile[row * 32 + c8] = v;
    }
    // stage B: 64x32 bf16 (1x uint4 per thread)
    {
      const int d = tid >> 2, c8 = (tid & 3) * 8;
      *(uint4*)&Btile[d * 32 + c8] =
          *(const uint4*)(Bsrc + (size_t)d * bstr + acol + c8);
    }
    __syncthreads();
    short8 af[2], bf_[4];
#pragma unroll
    for (int mi = 0; mi < 2; ++mi)
      af[mi] = *(const short8*)&Atile[(wave * 32 + mi * 16 + lc) * 32 + quad * 8];
#pragma unroll
    for (int ni = 0; ni < 4; ++ni)
      bf_[ni] = *(const short8*)&Btile[(ni * 16 + lc) * 32 + quad * 8];
#pragma unroll
    for (int mi = 0; mi < 2; ++mi)
#pragma unroll
      for (int ni = 0; ni < 4; ++ni)
        acc[mi][ni] = __builtin_amdgcn_mfma_f32_16x16x32_bf16(
            af[mi], bf_[ni], acc[mi][ni], 0, 0, 0);
  }

  // epilogue: + bias + temporal, write out
  const int b = bt / 12, t = bt - b * 12;
  const float sgn = (t & 1) ? -1.f : 1.f;
#pragma unroll
  for (int ni = 0; ni < 4; ++ni) {
    const int d = ni * 16 + lc;
    const float bias = bmlp[d];
#pragma unroll
    for (int mi = 0; mi < 2; ++mi) {
#pragma unroll
      for (int reg = 0; reg < 4; ++reg) {
        const int n = m0 + wave * 32 + mi * 16 + quad * 4 + reg;
        if (n >= 325) continue;
        const float v = ws[OFF_VT + ((size_t)b * 3900 + (size_t)n * 12 + t) * 64 + d];
        const float al = ws[OFF_ALT + ((size_t)b * 325 + n) * 64 + d];
        const float te = (v - sgn * al * (1.f / 12.f)) * (1.f / 6.f);
        out[((size_t)bt * 325 + n) * 64 + d] = acc[mi][ni][reg] + bias + te;
      }
    }
  }
}

extern "C" void kernel_launch(void* const* d_in, const int* in_sizes, int n_in,
                              void* d_out, int out_size, void* d_ws, size_t ws_size,
                              hipStream_t stream) {
  const float* x = (const float*)d_in[0];
  const float* adj = (const float*)d_in[1];
  const float* Wq_g = (const float*)d_in[2];
  const float* Wk_g = (const float*)d_in[3];
  const float* Wv_g = (const float*)d_in[4];
  // d_in[5], d_in[6] (Wq_t, Wk_t), d_in[12] (weights_Q_t), d_in[14] (t_modes):
  // dead code — temporal softmax axis == mean axis => out = vf/6.
  const float* Wv_t = (const float*)d_in[7];
  const float* Wfc1 = (const float*)d_in[8];
  const float* Wmlp = (const float*)d_in[9];
  const float* bmlp = (const float*)d_in[10];
  const float* wQ = (const float*)d_in[11];
  const int* sp_modes = (const int*)d_in[13];
  float* ws = (float*)d_ws;
  float* out = (float*)d_out;

  (void)in_sizes; (void)n_in; (void)out_size; (void)ws_size;

  hipMemsetAsync(ws + OFF_G, 0, 4096 * sizeof(float), stream);
  hipMemsetAsync(ws + OFF_XCT, 0, (size_t)384 * 22528 * sizeof(u16), stream);  // zero n-pads
  k_gram<<<256, 256, 0, stream>>>(x, ws);
  k_prep<<<367, 256, 0, stream>>>(adj, Wq_g, Wk_g, Wmlp, Wfc1, wQ, sp_modes, ws);
  k_spatial2<<<384, 256, 0, stream>>>(x, Wq_g, Wk_g, Wv_g, ws);
  k_linear<<<1950, 256, 0, stream>>>(x, Wv_t, ws);
  k_alt<<<2600, 256, 0, stream>>>(ws);
  k_final2<<<1152, 256, 0, stream>>>(bmlp, ws, out);
}

// Round 7
// 330.400 us; speedup vs baseline: 2.3360x; 1.1041x over previous
//
#include <hip/hip_runtime.h>

// Problem: B=32,T=12,N=325,D=64,H=4,HD=16,M_SP=32,M_T=6, SCALE=0.25
// Inputs fp32 (+ int32 mode lists); output fp32.
//
// Key identities used:
//  * temporal branch: softmax axis == mean axis  =>  out = vf/6. Whole branch is
//    v=x@Wv_t^T (fake (n',t') reshape r = n'*12+t'), drop Nyquist of 12-pt rfft, /6:
//    te[t'] = (v[t'] - (-1)^{t'} * (sum_s (-1)^s v[s]) / 12) / 6
//  * rfft over n commutes with channel linear => one DFT of x, then 64x64 matmuls.
//  * ||x@W^T||_F^2 = sum_{e,e'} (W^T W)[e,e'] * G[e,e'],  G = sum_rows x x^T.
//  * GCN: Wc = W_mlp @ W_fc1 folded; out = A_rownorm @ (x @ Wc^T) + b.
//
// R3: k_final -> MFMA.  R4: XCT transpose fix.
// R5: k_spatial -> MFMA (k_spatial3). TB rows interleaved so |.|^2 via shfl_xor(16).
// R6 fix: xfl/Wt3 were stored stride-40 but hold 64 columns -> rows aliased
//     (spatial branch scrambled, absmax 3.6e-2). Now chunked [2][rows][40].

typedef unsigned short u16;
typedef short short8 __attribute__((ext_vector_type(8)));
typedef float floatx4 __attribute__((ext_vector_type(4)));

__device__ __forceinline__ u16 f2bf(float f) {
  union { float fp; unsigned int u; } v; v.fp = f;
  unsigned int x = v.u;
  x += 0x7FFF + ((x >> 16) & 1);   // RNE
  return (u16)(x >> 16);
}

// ---- workspace layout (float offsets; u16 arrays count as size/2 floats) ----
constexpr size_t OFF_G    = 0;          // 4096    Gram (memset each launch)
constexpr size_t OFF_NORM = 4096;       // 16      [0]=1/||q||, [1]=1/||k||
constexpr size_t OFF_WC   = 4112;       // 4096    Wc = Wmlp@Wfc1
constexpr size_t OFF_WQA  = 8208;       // 15872   |weights_Q|
constexpr size_t OFF_ANB  = 24080;      // u16[325*352]   row-norm adj, bf16, col-pad 352
constexpr size_t OFF_TB   = 81280;      // u16[64*352]    DFT matrix bf16, rows interleaved re/im
constexpr size_t OFF_T2   = 102080;     // u16[325*64]    irfft: [n][2j]=wc_j cos, [n][2j+1]=-wc_j sin
constexpr size_t OFF_OFT  = 112480;     // u16[384*64*64] spectrum [bt][d][2j|2j+1] (re,im)
constexpr size_t OFF_XCT  = 898912;     // u16[384*64*352] xc transposed [bt][d][n], n-pad 352
constexpr size_t OFF_VT   = 5224288;    // f32[124800*64]  x @ Wv_t^T
constexpr size_t OFF_ALT  = 13211488;   // f32[665600]     alternating sums
// total = 13,877,088 floats = 55.5 MB

// =====================  K1: Gram matrix G = sum_rows x x^T  =====================
__global__ __launch_bounds__(256) void k_gram(const float* __restrict__ x,
                                              float* __restrict__ ws) {
  __shared__ __align__(16) float xs[2048];   // [32 rows][64]
  const int tid = threadIdx.x;
  const int e0 = (tid >> 4) << 2;
  const int f0 = (tid & 15) << 2;
  float acc[4][4] = {};
  const int ROWS = 124800;  // B*T*N
  for (int r0 = blockIdx.x * 32; r0 < ROWS; r0 += gridDim.x * 32) {
    const float4* src = (const float4*)(x + (size_t)r0 * 64);
    float4* dst = (float4*)xs;
    for (int i = tid; i < 512; i += 256) dst[i] = src[i];
    __syncthreads();
    for (int rr = 0; rr < 32; ++rr) {
      float a[4], b[4];
#pragma unroll
      for (int i = 0; i < 4; ++i) a[i] = xs[rr * 64 + e0 + i];
#pragma unroll
      for (int j = 0; j < 4; ++j) b[j] = xs[rr * 64 + f0 + j];
#pragma unroll
      for (int i = 0; i < 4; ++i)
#pragma unroll
        for (int j = 0; j < 4; ++j) acc[i][j] = fmaf(a[i], b[j], acc[i][j]);
    }
    __syncthreads();
  }
#pragma unroll
  for (int i = 0; i < 4; ++i)
#pragma unroll
    for (int j = 0; j < 4; ++j)
      atomicAdd(&ws[OFF_G + (size_t)(e0 + i) * 64 + f0 + j], acc[i][j]);
}

// ===========  K2: norms, Wc, |wQ|, adj row-norm (bf16), twiddle tables  ===========
__global__ __launch_bounds__(256) void k_prep(const float* __restrict__ adj,
                                              const float* __restrict__ Wq,
                                              const float* __restrict__ Wk,
                                              const float* __restrict__ Wmlp,
                                              const float* __restrict__ Wfc1,
                                              const float* __restrict__ wQ,
                                              const int* __restrict__ sp_modes,
                                              float* __restrict__ ws) {
  __shared__ float ldsw[2 * 64 * 65];
  __shared__ float partial[4];
  __shared__ float red[256];
  const int tid = threadIdx.x;
  const int blk = blockIdx.x;
  if (blk == 0) {
    for (int i = tid; i < 4096; i += 256) {
      int dd = i >> 6, e = i & 63;
      ldsw[dd * 65 + e] = Wq[i];
      ldsw[4160 + dd * 65 + e] = Wk[i];
    }
    __syncthreads();
    const int wave = tid >> 6, lane = tid & 63;
    const float* Wl = ldsw + ((wave >= 2) ? 4160 : 0);
    const int e0 = (wave & 1) * 32;
    float s = 0.f;
    for (int e = e0; e < e0 + 32; ++e) {
      const float* Gr = ws + OFF_G + (size_t)e * 64;
      float t = 0.f;
      for (int e2 = 0; e2 < 64; ++e2) t = fmaf(Gr[e2], Wl[lane * 65 + e2], t);
      s += Wl[lane * 65 + e] * t;
    }
    for (int off = 32; off > 0; off >>= 1) s += __shfl_down(s, off);
    if (lane == 0) partial[wave] = s;
    __syncthreads();
    if (tid == 0) {
      ws[OFF_NORM + 0] = rsqrtf(partial[0] + partial[1]);
      ws[OFF_NORM + 1] = rsqrtf(partial[2] + partial[3]);
    }
  } else if (blk == 1) {
    for (int o = tid; o < 4096; o += 256) {
      int g = o >> 6, dd = o & 63;
      float s = 0.f;
      for (int e = 0; e < 64; ++e)
        s = fmaf(Wmlp[g * 64 + e], Wfc1[e * 64 + dd], s);
      ws[OFF_WC + o] = s;
    }
  } else if (blk < 10) {
    for (int i = (blk - 2) * 256 + tid; i < 15872; i += 2048)
      ws[OFF_WQA + i] = fabsf(wQ[i]);
  } else if (blk < 335) {
    const int n = blk - 10;
    float p = 0.f;
    for (int k = tid; k < 325; k += 256) p += adj[n * 325 + k];
    red[tid] = p;
    __syncthreads();
    for (int s2 = 128; s2 > 0; s2 >>= 1) {
      if (tid < s2) red[tid] += red[tid + s2];
      __syncthreads();
    }
    const float inv = 1.f / red[0];
    u16* ANB = (u16*)(ws + OFF_ANB);
    for (int k = tid; k < 352; k += 256)
      ANB[(size_t)n * 352 + k] = (k < 325) ? f2bf(adj[n * 325 + k] * inv) : (u16)0;
  } else {
    const int j = blk - 335;  // < 32
    const int f = sp_modes[j];
    const float wgt = (f == 0) ? 1.f : 2.f;
    u16* T2B = (u16*)(ws + OFF_T2);
    u16* TB = (u16*)(ws + OFF_TB);
    // interleaved row order: rows 8g+0..3 = re f(4g..4g+3); 8g+4..7 = im
    const int row_re = 8 * (j >> 2) + (j & 3);
    const int row_im = row_re + 4;
    for (int n = tid; n < 352; n += 256) {
      float c = 0.f, s = 0.f;
      if (n < 325) {
        int mm = (f * n) % 325;               // exact range reduction
        float th = 6.283185307179586f * (float)mm * (1.f / 325.f);
        c = cosf(th);
        s = sinf(th);
      }
      TB[(size_t)row_re * 352 + n] = f2bf(c);
      TB[(size_t)row_im * 352 + n] = f2bf(-s);
      if (n < 325) {
        T2B[(size_t)n * 64 + 2 * j] = f2bf(wgt * (1.f / 325.f) * c);
        T2B[(size_t)n * 64 + 2 * j + 1] = f2bf(-wgt * (1.f / 325.f) * s);
      }
    }
  }
}

// =======  K3: spatial branch per bt — MFMA DFT + MFMA projection + softmax  =======
// Phase A: xf[64 mrows][64 e] = TB[64][352] @ x_bt[352][64]   (m rows re/im-interleaved)
// Phase B: pf[64][192] = xf @ [Wq|Wk|Wv]^T
// Phase C: |q|^2,|k|^2 via shfl_xor(16); softmax; OFT bf16.
__global__ __launch_bounds__(256) void k_spatial3(const float* __restrict__ x,
                                                  const float* __restrict__ Wq,
                                                  const float* __restrict__ Wk,
                                                  const float* __restrict__ Wv,
                                                  float* __restrict__ ws) {
  __shared__ __align__(16) float smem[10240];   // 40,960 B
  const int tid = threadIdx.x;
  const int bt = blockIdx.x;
  const int lane = tid & 63, wv = tid >> 6;
  const int lc = lane & 15, quad = lane >> 4;

  // ---------------- Phase A: DFT GEMM ----------------
  u16* Atile = (u16*)smem;              // [64][40]  5120 B
  u16* Btile = (u16*)smem + 2560;       // [64 e][40 k]  5120 B (e-major)
  const u16* TB = (const u16*)(ws + OFF_TB);
  const float* xb = x + (size_t)bt * 20800;
  floatx4 accA[4] = {};
  {
    const int arow = tid >> 2, ac8 = (tid & 3) * 8;     // A stage map
    const int br = tid & 31, be0 = (tid >> 5) * 8;      // B stage map
    for (int kc = 0; kc < 11; ++kc) {
      const int k0 = kc * 32;
      __syncthreads();
      *(uint4*)&Atile[arow * 40 + ac8] = *(const uint4*)&TB[(size_t)arow * 352 + k0 + ac8];
      {
        float v[8];
        if (k0 + br < 325) {
          const float* src = xb + (size_t)(k0 + br) * 64 + be0;
          *(float4*)v = *(const float4*)src;
          *(float4*)(v + 4) = *(const float4*)(src + 4);
        } else {
#pragma unroll
          for (int u = 0; u < 8; ++u) v[u] = 0.f;
        }
#pragma unroll
        for (int u = 0; u < 8; ++u) Btile[(be0 + u) * 40 + br] = f2bf(v[u]);
      }
      __syncthreads();
      const short8 af = *(const short8*)&Atile[(16 * wv + lc) * 40 + quad * 8];
#pragma unroll
      for (int t = 0; t < 4; ++t) {
        const short8 bf_ = *(const short8*)&Btile[(t * 16 + lc) * 40 + quad * 8];
        accA[t] = __builtin_amdgcn_mfma_f32_16x16x32_bf16(af, bf_, accA[t], 0, 0, 0);
      }
    }
  }
  __syncthreads();
  // R6 fix: xf and W staged CHUNKED by 32-e halves, stride-40 rows (no row aliasing).
  u16* xfl2 = (u16*)smem;               // [2 chunk][64 m][40]   u16 0..5119
  u16* Wt3b = (u16*)smem + 5120;        // [2 chunk][192 d][40]  u16 5120..20479
#pragma unroll
  for (int t = 0; t < 4; ++t)
#pragma unroll
    for (int r = 0; r < 4; ++r)
      xfl2[(t >> 1) * 2560 + (16 * wv + quad * 4 + r) * 40 + (t & 1) * 16 + lc] =
          f2bf(accA[t][r]);
  for (int i = tid; i < 3072; i += 256) {
    const int row = i >> 4, e0 = (i & 15) * 4;
    const float* Wm = (row < 64) ? Wq : (row < 128) ? Wk : Wv;
    const float4 v = *(const float4*)(Wm + (size_t)(row & 63) * 64 + e0);
    u16* dst = &Wt3b[(e0 >> 5) * 7680 + row * 40 + (e0 & 31)];
    dst[0] = f2bf(v.x); dst[1] = f2bf(v.y); dst[2] = f2bf(v.z); dst[3] = f2bf(v.w);
  }
  __syncthreads();

  // ---------------- Phase B: projection GEMM ----------------
  floatx4 acc2[12] = {};
#pragma unroll
  for (int kc2 = 0; kc2 < 2; ++kc2) {
    const short8 af2 = *(const short8*)&xfl2[kc2 * 2560 + (16 * wv + lc) * 40 + quad * 8];
#pragma unroll
    for (int t = 0; t < 12; ++t) {
      const short8 bf2 = *(const short8*)&Wt3b[kc2 * 7680 + (t * 16 + lc) * 40 + quad * 8];
      acc2[t] = __builtin_amdgcn_mfma_f32_16x16x32_bf16(af2, bf2, acc2[t], 0, 0, 0);
    }
  }
  __syncthreads();

  // ---------------- Phase C ----------------
  float* sq_q = smem;             // [32][64]
  float* sq_k = smem + 2048;      // [32][64] -> absk*SCALE/||k||
  float* vfre = smem + 4096;
  float* vfim = smem + 6144;
  float* wbar = smem + 8192;
  for (int i = tid; i < 2048; i += 256) wbar[i] = 0.f;
  {
    const int fb = 8 * wv + ((quad >= 2) ? 4 : 0);
    const int isim = quad & 1;
#pragma unroll
    for (int t = 0; t < 12; ++t) {
      const int mat = t >> 2;
      const int d = (t & 3) * 16 + lc;
#pragma unroll
      for (int r = 0; r < 4; ++r) {
        const float v = acc2[t][r];
        if (mat == 2) {
          if (isim) vfim[(fb + r) * 64 + d] = v;
          else vfre[(fb + r) * 64 + d] = v;
        } else {
          const float s2 = v * v + __shfl_xor(v * v, 16);
          if (!isim) {
            if (mat == 0) sq_q[(fb + r) * 64 + d] = s2;
            else sq_k[(fb + r) * 64 + d] = s2;
          }
        }
      }
    }
  }
  __syncthreads();
  const float inv_nq = ws[OFF_NORM + 0];
  const float inv_nk = ws[OFF_NORM + 1];
  for (int i = tid; i < 2048; i += 256)
    sq_k[i] = 0.25f * inv_nk * sqrtf(sq_k[i]);
  __syncthreads();
  {
    const int d = tid & 63, fb2 = tid >> 6, hd = d & 15;
    const float* wqa = ws + OFF_WQA;
    float wacc[32];
#pragma unroll
    for (int j = 0; j < 32; ++j) wacc[j] = 0.f;
    for (int r8 = 0; r8 < 8; ++r8) {
      const int m = fb2 + (r8 << 2);
      const float aq = inv_nq * sqrtf(sq_q[m * 64 + d]);
      float sv[32];
      float mx = -1e30f;
#pragma unroll
      for (int j = 0; j < 32; ++j) {
        const float a = (j == 0) ? aq : wqa[(m * 31 + (j - 1)) * 16 + hd];
        const float s = sq_k[j * 64 + d] * a;
        sv[j] = s;
        mx = fmaxf(mx, s);
      }
      float sum = 0.f;
#pragma unroll
      for (int j = 0; j < 32; ++j) {
        const float ev = __expf(sv[j] - mx);
        sv[j] = ev;
        sum += ev;
      }
      const float sc = 0.03125f / sum;
#pragma unroll
      for (int j = 0; j < 32; ++j) wacc[j] += sv[j] * sc;
    }
#pragma unroll
    for (int j = 0; j < 32; ++j) atomicAdd(&wbar[j * 64 + d], wacc[j]);
  }
  __syncthreads();
  // OFT[bt][d][2j|2j+1] packed bf16, coalesced uint writes
  unsigned int* OFTu = (unsigned int*)(ws + OFF_OFT) + (size_t)bt * 2048;
  for (int i2 = tid; i2 < 2048; i2 += 256) {
    const int d = i2 >> 5, j = i2 & 31;
    const float w = wbar[j * 64 + d];
    const unsigned int lo = f2bf(vfre[j * 64 + d] * w);
    const unsigned int hi = f2bf(vfim[j * 64 + d] * w);
    OFTu[i2] = lo | (hi << 16);
  }
}

// =======  K4: xc = x @ Wc^T (-> XCT bf16 transposed), vt = x @ Wv_t^T (f32)  =======
__global__ __launch_bounds__(256) void k_linear(const float* __restrict__ x,
                                                const float* __restrict__ Wvt,
                                                float* __restrict__ ws) {
  __shared__ __align__(16) float xlds[4160];   // [64][65]: x staged [row][64], then xc^T [chan][row] pad-65
  __shared__ float wct[64 * 65];
  __shared__ float wvt[64 * 65];
  const int tid = threadIdx.x;
  const size_t base = (size_t)blockIdx.x * 64;  // 1950 blocks * 64 rows
  {
    const float4* src = (const float4*)(x + base * 64);
    for (int i = tid; i < 1024; i += 256)
      ((float4*)xlds)[i] = src[i];
  }
  for (int i = tid; i < 4096; i += 256) {
    int o = i >> 6, e = i & 63;
    wct[o * 65 + e] = ws[OFF_WC + i];
    wvt[o * 65 + e] = Wvt[i];
  }
  __syncthreads();
  const int c = tid & 63, rg = tid >> 6;
  float a1v[16];
  for (int k = 0; k < 16; ++k) {
    const int r = rg * 16 + k;
    float a1 = 0.f, a2 = 0.f;
    for (int e = 0; e < 64; ++e) {
      float xv = xlds[r * 64 + e];
      a1 = fmaf(xv, wct[c * 65 + e], a1);
      a2 = fmaf(xv, wvt[c * 65 + e], a2);
    }
    a1v[k] = a1;
    ws[OFF_VT + (base + r) * 64 + c] = a2;
  }
  __syncthreads();   // done reading xlds
  for (int k = 0; k < 16; ++k)
    xlds[c * 65 + rg * 16 + k] = a1v[k];   // [channel c][row r] pad-65
  __syncthreads();
  u16* XCT = (u16*)(ws + OFF_XCT);
  for (int i = tid; i < 4096; i += 256) {
    const int d = i >> 6, idx = i & 63;     // d = channel, idx = local row
    const unsigned int r = (unsigned int)(base + idx);
    const unsigned int bt = r / 325u;
    const unsigned int n = r - bt * 325u;
    XCT[(size_t)bt * 22528 + (size_t)d * 352 + n] = f2bf(xlds[d * 65 + idx]);
  }
}

// =======  K5: alt[b,n',d] = sum_s (-1)^s vt[b, n'*12+s, d]  =======
__global__ __launch_bounds__(256) void k_alt(float* __restrict__ ws) {
  const int idx = blockIdx.x * 256 + threadIdx.x;
  if (idx >= 32 * 325 * 64) return;
  const int dd = idx & 63;
  const int n = (idx >> 6) % 325;
  const int b = idx / (64 * 325);
  const float* vt = ws + OFF_VT + ((size_t)b * 3900 + (size_t)n * 12) * 64 + dd;
  float s = 0.f, sign = 1.f;
  for (int k = 0; k < 12; ++k) {
    s += sign * vt[k * 64];
    sign = -sign;
  }
  ws[OFF_ALT + idx] = s;
}

// =======  K6: MFMA — C = AN@XCT + T2@OFT, + temporal + bias -> out  =======
__global__ __launch_bounds__(256) void k_final2(const float* __restrict__ bmlp,
                                                float* __restrict__ ws,
                                                float* __restrict__ out) {
  __shared__ __align__(16) u16 Atile[128 * 32];   // 8 KB
  __shared__ __align__(16) u16 Btile[64 * 32];    // 4 KB
  const int tid = threadIdx.x;
  const int bt = blockIdx.x / 3, mc = blockIdx.x % 3;
  const int m0 = mc * 128;
  const int wave = tid >> 6, lane = tid & 63;
  const int quad = lane >> 4, lc = lane & 15;

  const u16* ANB = (const u16*)(ws + OFF_ANB);
  const u16* T2B = (const u16*)(ws + OFF_T2);
  const u16* XCT = (const u16*)(ws + OFF_XCT) + (size_t)bt * 22528;
  const u16* OFT = (const u16*)(ws + OFF_OFT) + (size_t)bt * 4096;

  floatx4 acc[2][4] = {};

  for (int c13 = 0; c13 < 13; ++c13) {
    const bool gcn = (c13 < 11);
    const u16* Asrc = gcn ? ANB : T2B;
    const int astr = gcn ? 352 : 64;
    const int acol = gcn ? c13 * 32 : (c13 - 11) * 32;
    const u16* Bsrc = gcn ? XCT : OFT;
    const int bstr = gcn ? 352 : 64;
    __syncthreads();
    for (int i = tid; i < 512; i += 256) {
      const int row = i >> 2, c8 = (i & 3) * 8;
      const int gr = m0 + row;
      uint4 v = make_uint4(0, 0, 0, 0);
      if (gr < 325)
        v = *(const uint4*)(Asrc + (size_t)gr * astr + acol + c8);
      *(uint4*)&Atile[row * 32 + c8] = v;
    }
    {
      const int d = tid >> 2, c8 = (tid & 3) * 8;
      *(uint4*)&Btile[d * 32 + c8] =
          *(const uint4*)(Bsrc + (size_t)d * bstr + acol + c8);
    }
    __syncthreads();
    short8 af[2], bf_[4];
#pragma unroll
    for (int mi = 0; mi < 2; ++mi)
      af[mi] = *(const short8*)&Atile[(wave * 32 + mi * 16 + lc) * 32 + quad * 8];
#pragma unroll
    for (int ni = 0; ni < 4; ++ni)
      bf_[ni] = *(const short8*)&Btile[(ni * 16 + lc) * 32 + quad * 8];
#pragma unroll
    for (int mi = 0; mi < 2; ++mi)
#pragma unroll
      for (int ni = 0; ni < 4; ++ni)
        acc[mi][ni] = __builtin_amdgcn_mfma_f32_16x16x32_bf16(
            af[mi], bf_[ni], acc[mi][ni], 0, 0, 0);
  }

  const int b = bt / 12, t = bt - b * 12;
  const float sgn = (t & 1) ? -1.f : 1.f;
#pragma unroll
  for (int ni = 0; ni < 4; ++ni) {
    const int d = ni * 16 + lc;
    const float bias = bmlp[d];
#pragma unroll
    for (int mi = 0; mi < 2; ++mi) {
#pragma unroll
      for (int reg = 0; reg < 4; ++reg) {
        const int n = m0 + wave * 32 + mi * 16 + quad * 4 + reg;
        if (n >= 325) continue;
        const float v = ws[OFF_VT + ((size_t)b * 3900 + (size_t)n * 12 + t) * 64 + d];
        const float al = ws[OFF_ALT + ((size_t)b * 325 + n) * 64 + d];
        const float te = (v - sgn * al * (1.f / 12.f)) * (1.f / 6.f);
        out[((size_t)bt * 325 + n) * 64 + d] = acc[mi][ni][reg] + bias + te;
      }
    }
  }
}

extern "C" void kernel_launch(void* const* d_in, const int* in_sizes, int n_in,
                              void* d_out, int out_size, void* d_ws, size_t ws_size,
                              hipStream_t stream) {
  const float* x = (const float*)d_in[0];
  const float* adj = (const float*)d_in[1];
  const float* Wq_g = (const float*)d_in[2];
  const float* Wk_g = (const float*)d_in[3];
  const float* Wv_g = (const float*)d_in[4];
  // d_in[5], d_in[6] (Wq_t, Wk_t), d_in[12] (weights_Q_t), d_in[14] (t_modes):
  // dead code — temporal softmax axis == mean axis => out = vf/6.
  const float* Wv_t = (const float*)d_in[7];
  const float* Wfc1 = (const float*)d_in[8];
  const float* Wmlp = (const float*)d_in[9];
  const float* bmlp = (const float*)d_in[10];
  const float* wQ = (const float*)d_in[11];
  const int* sp_modes = (const int*)d_in[13];
  float* ws = (float*)d_ws;
  float* out = (float*)d_out;

  (void)in_sizes; (void)n_in; (void)out_size; (void)ws_size;

  hipMemsetAsync(ws + OFF_G, 0, 4096 * sizeof(float), stream);
  hipMemsetAsync(ws + OFF_XCT, 0, (size_t)384 * 22528 * sizeof(u16), stream);  // zero n-pads
  k_gram<<<256, 256, 0, stream>>>(x, ws);
  k_prep<<<367, 256, 0, stream>>>(adj, Wq_g, Wk_g, Wmlp, Wfc1, wQ, sp_modes, ws);
  k_spatial3<<<384, 256, 0, stream>>>(x, Wq_g, Wk_g, Wv_g, ws);
  k_linear<<<1950, 256, 0, stream>>>(x, Wv_t, ws);
  k_alt<<<2600, 256, 0, stream>>>(ws);
  k_final2<<<1152, 256, 0, stream>>>(bmlp, ws, out);
}

// Round 8
// 272.530 us; speedup vs baseline: 2.8320x; 1.2123x over previous
//
#include <hip/hip_runtime.h>

// Problem: B=32,T=12,N=325,D=64,H=4,HD=16,M_SP=32,M_T=6, SCALE=0.25
// Inputs fp32 (+ int32 mode lists); output fp32.
//
// Key identities used:
//  * temporal branch: softmax axis == mean axis  =>  out = vf/6. Whole branch is
//    v=x@Wv_t^T (fake (n',t') reshape r = n'*12+t'), drop Nyquist of 12-pt rfft, /6.
//  * rfft over n commutes with channel linear => one DFT of x, then 64x64 matmuls.
//  * norms: ||q||^2 computed directly as sum q^2 (q = x@Wq^T) — same FLOPs as Gram,
//    fused into the k_linear2 MFMA pass (R7; k_gram deleted).
//  * GCN: Wc = W_mlp @ W_fc1 folded; out = A_rownorm @ (x @ Wc^T) + b.
//
// R3: k_final -> MFMA.  R4: XCT transpose fix.  R5/R6: k_spatial -> MFMA.
// R7: k_gram deleted; k_linear2 = one MFMA pass producing xc (bf16 XCT), vt (f32),
//     and ||q||^2/||k||^2 partial sums (2 atomics/block). k_spatial3 rsqrtf inline.

typedef unsigned short u16;
typedef short short8 __attribute__((ext_vector_type(8)));
typedef float floatx4 __attribute__((ext_vector_type(4)));

__device__ __forceinline__ u16 f2bf(float f) {
  union { float fp; unsigned int u; } v; v.fp = f;
  unsigned int x = v.u;
  x += 0x7FFF + ((x >> 16) & 1);   // RNE
  return (u16)(x >> 16);
}

// ---- workspace layout (float offsets; u16 arrays count as size/2 floats) ----
constexpr size_t OFF_NORM = 4096;       // 2       [0]=sum q^2, [1]=sum k^2 (memset 0)
constexpr size_t OFF_WC   = 4112;       // 4096    Wc = Wmlp@Wfc1
constexpr size_t OFF_WQA  = 8208;       // 15872   |weights_Q|
constexpr size_t OFF_ANB  = 24080;      // u16[325*352]   row-norm adj, bf16, col-pad 352
constexpr size_t OFF_TB   = 81280;      // u16[64*352]    DFT matrix bf16, rows interleaved re/im
constexpr size_t OFF_T2   = 102080;     // u16[325*64]    irfft: [n][2j]=wc_j cos, [n][2j+1]=-wc_j sin
constexpr size_t OFF_OFT  = 112480;     // u16[384*64*64] spectrum [bt][d][2j|2j+1] (re,im)
constexpr size_t OFF_XCT  = 898912;     // u16[384*64*352] xc transposed [bt][d][n], n-pad 352
constexpr size_t OFF_VT   = 5224288;    // f32[124800*64]  x @ Wv_t^T
constexpr size_t OFF_ALT  = 13211488;   // f32[665600]     alternating sums

// ===========  K2: Wc, |wQ|, adj row-norm (bf16), twiddle tables  ===========
__global__ __launch_bounds__(256) void k_prep(const float* __restrict__ adj,
                                              const float* __restrict__ Wmlp,
                                              const float* __restrict__ Wfc1,
                                              const float* __restrict__ wQ,
                                              const int* __restrict__ sp_modes,
                                              float* __restrict__ ws) {
  __shared__ float red[256];
  const int tid = threadIdx.x;
  const int blk = blockIdx.x;
  if (blk == 0) {
    for (int o = tid; o < 4096; o += 256) {
      int g = o >> 6, dd = o & 63;
      float s = 0.f;
      for (int e = 0; e < 64; ++e)
        s = fmaf(Wmlp[g * 64 + e], Wfc1[e * 64 + dd], s);
      ws[OFF_WC + o] = s;
    }
  } else if (blk < 9) {
    for (int i = (blk - 1) * 256 + tid; i < 15872; i += 2048)
      ws[OFF_WQA + i] = fabsf(wQ[i]);
  } else if (blk < 334) {
    const int n = blk - 9;
    float p = 0.f;
    for (int k = tid; k < 325; k += 256) p += adj[n * 325 + k];
    red[tid] = p;
    __syncthreads();
    for (int s2 = 128; s2 > 0; s2 >>= 1) {
      if (tid < s2) red[tid] += red[tid + s2];
      __syncthreads();
    }
    const float inv = 1.f / red[0];
    u16* ANB = (u16*)(ws + OFF_ANB);
    for (int k = tid; k < 352; k += 256)
      ANB[(size_t)n * 352 + k] = (k < 325) ? f2bf(adj[n * 325 + k] * inv) : (u16)0;
  } else {
    const int j = blk - 334;  // < 32
    const int f = sp_modes[j];
    const float wgt = (f == 0) ? 1.f : 2.f;
    u16* T2B = (u16*)(ws + OFF_T2);
    u16* TB = (u16*)(ws + OFF_TB);
    // interleaved row order: rows 8g+0..3 = re f(4g..4g+3); 8g+4..7 = im
    const int row_re = 8 * (j >> 2) + (j & 3);
    const int row_im = row_re + 4;
    for (int n = tid; n < 352; n += 256) {
      float c = 0.f, s = 0.f;
      if (n < 325) {
        int mm = (f * n) % 325;               // exact range reduction
        float th = 6.283185307179586f * (float)mm * (1.f / 325.f);
        c = cosf(th);
        s = sinf(th);
      }
      TB[(size_t)row_re * 352 + n] = f2bf(c);
      TB[(size_t)row_im * 352 + n] = f2bf(-s);
      if (n < 325) {
        T2B[(size_t)n * 64 + 2 * j] = f2bf(wgt * (1.f / 325.f) * c);
        T2B[(size_t)n * 64 + 2 * j + 1] = f2bf(-wgt * (1.f / 325.f) * s);
      }
    }
  }
}

// =======  K4 (R7): one MFMA pass over x: xc->XCT, vt->VT, ||q||^2/||k||^2  =======
// 975 blocks x 128 rows. A = x[128][64] bf16 (stride 72: 36 dw = +4 banks/row, 2-way).
// B = [Wc | Wvt | Wq | Wk] 256 rows x 64. acc[2 m][16 n] per wave.
__global__ __launch_bounds__(256) void k_linear2(const float* __restrict__ x,
                                                 const float* __restrict__ Wvt,
                                                 const float* __restrict__ Wq,
                                                 const float* __restrict__ Wk,
                                                 float* __restrict__ ws) {
  __shared__ __align__(16) u16 XA[128 * 72];   // 18432 B
  __shared__ __align__(16) u16 WB[256 * 72];   // 36864 B; reused as xcT[64][132] after MFMA
  __shared__ float reds[8];
  const int tid = threadIdx.x;
  const int wv = tid >> 6, lane = tid & 63, lc = lane & 15, quad = lane >> 4;
  const size_t base = (size_t)blockIdx.x * 128;

  for (int i = tid; i < 2048; i += 256) {
    const int row = i >> 4, e0 = (i & 15) * 4;
    const float4 v = *(const float4*)(x + (base + row) * 64 + e0);
    u16* dst = &XA[row * 72 + e0];
    dst[0] = f2bf(v.x); dst[1] = f2bf(v.y); dst[2] = f2bf(v.z); dst[3] = f2bf(v.w);
  }
  for (int i = tid; i < 4096; i += 256) {
    const int row = i >> 4, e0 = (i & 15) * 4;
    const int g = row & 63, sel = row >> 6;
    const float* src = (sel == 0) ? (ws + OFF_WC + g * 64)
                     : (sel == 1) ? (Wvt + g * 64)
                     : (sel == 2) ? (Wq + g * 64)
                                  : (Wk + g * 64);
    const float4 v = *(const float4*)(src + e0);
    u16* dst = &WB[row * 72 + e0];
    dst[0] = f2bf(v.x); dst[1] = f2bf(v.y); dst[2] = f2bf(v.z); dst[3] = f2bf(v.w);
  }
  __syncthreads();

  floatx4 acc[2][16] = {};
#pragma unroll
  for (int kc = 0; kc < 2; ++kc) {
    short8 af[2];
#pragma unroll
    for (int mi = 0; mi < 2; ++mi)
      af[mi] = *(const short8*)&XA[(32 * wv + 16 * mi + lc) * 72 + kc * 32 + quad * 8];
#pragma unroll
    for (int ni = 0; ni < 16; ++ni) {
      const short8 bf_ = *(const short8*)&WB[(ni * 16 + lc) * 72 + kc * 32 + quad * 8];
#pragma unroll
      for (int mi = 0; mi < 2; ++mi)
        acc[mi][ni] = __builtin_amdgcn_mfma_f32_16x16x32_bf16(af[mi], bf_, acc[mi][ni], 0, 0, 0);
    }
  }

  // VT (f32) + q/k squared partial sums
  float sq = 0.f, sk = 0.f;
#pragma unroll
  for (int mi = 0; mi < 2; ++mi)
#pragma unroll
    for (int reg = 0; reg < 4; ++reg) {
      const int row = 32 * wv + 16 * mi + quad * 4 + reg;
#pragma unroll
      for (int ni = 0; ni < 4; ++ni)
        ws[OFF_VT + (base + row) * 64 + ni * 16 + lc] = acc[mi][4 + ni][reg];
#pragma unroll
      for (int ni = 0; ni < 4; ++ni) {
        const float v = acc[mi][8 + ni][reg];
        sq = fmaf(v, v, sq);
      }
#pragma unroll
      for (int ni = 0; ni < 4; ++ni) {
        const float v = acc[mi][12 + ni][reg];
        sk = fmaf(v, v, sk);
      }
    }
  for (int off = 32; off > 0; off >>= 1) {
    sq += __shfl_down(sq, off);
    sk += __shfl_down(sk, off);
  }
  if (lane == 0) { reds[wv] = sq; reds[4 + wv] = sk; }
  __syncthreads();   // also: all MFMA reads of WB complete past this point
  if (tid == 0) atomicAdd(&ws[OFF_NORM + 0], reds[0] + reds[1] + reds[2] + reds[3]);
  if (tid == 1) atomicAdd(&ws[OFF_NORM + 1], reds[4] + reds[5] + reds[6] + reds[7]);

  // xc -> xcT[64 d][132] bf16 in WB area (stride 132: 66 dw = +2 banks/lane, clean)
  u16* xcT = WB;
#pragma unroll
  for (int mi = 0; mi < 2; ++mi)
#pragma unroll
    for (int ni = 0; ni < 4; ++ni)
#pragma unroll
      for (int reg = 0; reg < 4; ++reg)
        xcT[(ni * 16 + lc) * 132 + 32 * wv + 16 * mi + quad * 4 + reg] =
            f2bf(acc[mi][ni][reg]);
  __syncthreads();
  u16* XCT = (u16*)(ws + OFF_XCT);
  for (int i = tid; i < 8192; i += 256) {
    const int d = i >> 7, r = i & 127;
    const unsigned int row = (unsigned int)(base + r);
    const unsigned int bt = row / 325u;
    const unsigned int n = row - bt * 325u;
    XCT[(size_t)bt * 22528 + (size_t)d * 352 + n] = xcT[d * 132 + r];
  }
}

// =======  K3: spatial branch per bt — MFMA DFT + MFMA projection + softmax  =======
__global__ __launch_bounds__(256) void k_spatial3(const float* __restrict__ x,
                                                  const float* __restrict__ Wq,
                                                  const float* __restrict__ Wk,
                                                  const float* __restrict__ Wv,
                                                  float* __restrict__ ws) {
  __shared__ __align__(16) float smem[10240];   // 40,960 B
  const int tid = threadIdx.x;
  const int bt = blockIdx.x;
  const int lane = tid & 63, wv = tid >> 6;
  const int lc = lane & 15, quad = lane >> 4;

  // ---------------- Phase A: DFT GEMM ----------------
  u16* Atile = (u16*)smem;              // [64][40]  5120 B
  u16* Btile = (u16*)smem + 2560;       // [64 e][40 k]  5120 B (e-major)
  const u16* TB = (const u16*)(ws + OFF_TB);
  const float* xb = x + (size_t)bt * 20800;
  floatx4 accA[4] = {};
  {
    const int arow = tid >> 2, ac8 = (tid & 3) * 8;     // A stage map
    const int br = tid & 31, be0 = (tid >> 5) * 8;      // B stage map
    for (int kc = 0; kc < 11; ++kc) {
      const int k0 = kc * 32;
      __syncthreads();
      *(uint4*)&Atile[arow * 40 + ac8] = *(const uint4*)&TB[(size_t)arow * 352 + k0 + ac8];
      {
        float v[8];
        if (k0 + br < 325) {
          const float* src = xb + (size_t)(k0 + br) * 64 + be0;
          *(float4*)v = *(const float4*)src;
          *(float4*)(v + 4) = *(const float4*)(src + 4);
        } else {
#pragma unroll
          for (int u = 0; u < 8; ++u) v[u] = 0.f;
        }
#pragma unroll
        for (int u = 0; u < 8; ++u) Btile[(be0 + u) * 40 + br] = f2bf(v[u]);
      }
      __syncthreads();
      const short8 af = *(const short8*)&Atile[(16 * wv + lc) * 40 + quad * 8];
#pragma unroll
      for (int t = 0; t < 4; ++t) {
        const short8 bf_ = *(const short8*)&Btile[(t * 16 + lc) * 40 + quad * 8];
        accA[t] = __builtin_amdgcn_mfma_f32_16x16x32_bf16(af, bf_, accA[t], 0, 0, 0);
      }
    }
  }
  __syncthreads();
  // xf and W staged CHUNKED by 32-e halves, stride-40 rows (no row aliasing).
  u16* xfl2 = (u16*)smem;               // [2 chunk][64 m][40]   u16 0..5119
  u16* Wt3b = (u16*)smem + 5120;        // [2 chunk][192 d][40]  u16 5120..20479
#pragma unroll
  for (int t = 0; t < 4; ++t)
#pragma unroll
    for (int r = 0; r < 4; ++r)
      xfl2[(t >> 1) * 2560 + (16 * wv + quad * 4 + r) * 40 + (t & 1) * 16 + lc] =
          f2bf(accA[t][r]);
  for (int i = tid; i < 3072; i += 256) {
    const int row = i >> 4, e0 = (i & 15) * 4;
    const float* Wm = (row < 64) ? Wq : (row < 128) ? Wk : Wv;
    const float4 v = *(const float4*)(Wm + (size_t)(row & 63) * 64 + e0);
    u16* dst = &Wt3b[(e0 >> 5) * 7680 + row * 40 + (e0 & 31)];
    dst[0] = f2bf(v.x); dst[1] = f2bf(v.y); dst[2] = f2bf(v.z); dst[3] = f2bf(v.w);
  }
  __syncthreads();

  // ---------------- Phase B: projection GEMM ----------------
  floatx4 acc2[12] = {};
#pragma unroll
  for (int kc2 = 0; kc2 < 2; ++kc2) {
    const short8 af2 = *(const short8*)&xfl2[kc2 * 2560 + (16 * wv + lc) * 40 + quad * 8];
#pragma unroll
    for (int t = 0; t < 12; ++t) {
      const short8 bf2 = *(const short8*)&Wt3b[kc2 * 7680 + (t * 16 + lc) * 40 + quad * 8];
      acc2[t] = __builtin_amdgcn_mfma_f32_16x16x32_bf16(af2, bf2, acc2[t], 0, 0, 0);
    }
  }
  __syncthreads();

  // ---------------- Phase C ----------------
  float* sq_q = smem;             // [32][64]
  float* sq_k = smem + 2048;      // [32][64] -> absk*SCALE/||k||
  float* vfre = smem + 4096;
  float* vfim = smem + 6144;
  float* wbar = smem + 8192;
  for (int i = tid; i < 2048; i += 256) wbar[i] = 0.f;
  {
    const int fb = 8 * wv + ((quad >= 2) ? 4 : 0);
    const int isim = quad & 1;
#pragma unroll
    for (int t = 0; t < 12; ++t) {
      const int mat = t >> 2;
      const int d = (t & 3) * 16 + lc;
#pragma unroll
      for (int r = 0; r < 4; ++r) {
        const float v = acc2[t][r];
        if (mat == 2) {
          if (isim) vfim[(fb + r) * 64 + d] = v;
          else vfre[(fb + r) * 64 + d] = v;
        } else {
          const float s2 = v * v + __shfl_xor(v * v, 16);
          if (!isim) {
            if (mat == 0) sq_q[(fb + r) * 64 + d] = s2;
            else sq_k[(fb + r) * 64 + d] = s2;
          }
        }
      }
    }
  }
  __syncthreads();
  const float inv_nq = rsqrtf(ws[OFF_NORM + 0]);
  const float inv_nk = rsqrtf(ws[OFF_NORM + 1]);
  for (int i = tid; i < 2048; i += 256)
    sq_k[i] = 0.25f * inv_nk * sqrtf(sq_k[i]);
  __syncthreads();
  {
    const int d = tid & 63, fb2 = tid >> 6, hd = d & 15;
    const float* wqa = ws + OFF_WQA;
    float wacc[32];
#pragma unroll
    for (int j = 0; j < 32; ++j) wacc[j] = 0.f;
    for (int r8 = 0; r8 < 8; ++r8) {
      const int m = fb2 + (r8 << 2);
      const float aq = inv_nq * sqrtf(sq_q[m * 64 + d]);
      float sv[32];
      float mx = -1e30f;
#pragma unroll
      for (int j = 0; j < 32; ++j) {
        const float a = (j == 0) ? aq : wqa[(m * 31 + (j - 1)) * 16 + hd];
        const float s = sq_k[j * 64 + d] * a;
        sv[j] = s;
        mx = fmaxf(mx, s);
      }
      float sum = 0.f;
#pragma unroll
      for (int j = 0; j < 32; ++j) {
        const float ev = __expf(sv[j] - mx);
        sv[j] = ev;
        sum += ev;
      }
      const float sc = 0.03125f / sum;
#pragma unroll
      for (int j = 0; j < 32; ++j) wacc[j] += sv[j] * sc;
    }
#pragma unroll
    for (int j = 0; j < 32; ++j) atomicAdd(&wbar[j * 64 + d], wacc[j]);
  }
  __syncthreads();
  // OFT[bt][d][2j|2j+1] packed bf16, coalesced uint writes
  unsigned int* OFTu = (unsigned int*)(ws + OFF_OFT) + (size_t)bt * 2048;
  for (int i2 = tid; i2 < 2048; i2 += 256) {
    const int d = i2 >> 5, j = i2 & 31;
    const float w = wbar[j * 64 + d];
    const unsigned int lo = f2bf(vfre[j * 64 + d] * w);
    const unsigned int hi = f2bf(vfim[j * 64 + d] * w);
    OFTu[i2] = lo | (hi << 16);
  }
}

// =======  K5: alt[b,n',d] = sum_s (-1)^s vt[b, n'*12+s, d]  =======
__global__ __launch_bounds__(256) void k_alt(float* __restrict__ ws) {
  const int idx = blockIdx.x * 256 + threadIdx.x;
  if (idx >= 32 * 325 * 64) return;
  const int dd = idx & 63;
  const int n = (idx >> 6) % 325;
  const int b = idx / (64 * 325);
  const float* vt = ws + OFF_VT + ((size_t)b * 3900 + (size_t)n * 12) * 64 + dd;
  float s = 0.f, sign = 1.f;
  for (int k = 0; k < 12; ++k) {
    s += sign * vt[k * 64];
    sign = -sign;
  }
  ws[OFF_ALT + idx] = s;
}

// =======  K6: MFMA — C = AN@XCT + T2@OFT, + temporal + bias -> out  =======
__global__ __launch_bounds__(256) void k_final2(const float* __restrict__ bmlp,
                                                float* __restrict__ ws,
                                                float* __restrict__ out) {
  __shared__ __align__(16) u16 Atile[128 * 32];   // 8 KB
  __shared__ __align__(16) u16 Btile[64 * 32];    // 4 KB
  const int tid = threadIdx.x;
  const int bt = blockIdx.x / 3, mc = blockIdx.x % 3;
  const int m0 = mc * 128;
  const int wave = tid >> 6, lane = tid & 63;
  const int quad = lane >> 4, lc = lane & 15;

  const u16* ANB = (const u16*)(ws + OFF_ANB);
  const u16* T2B = (const u16*)(ws + OFF_T2);
  const u16* XCT = (const u16*)(ws + OFF_XCT) + (size_t)bt * 22528;
  const u16* OFT = (const u16*)(ws + OFF_OFT) + (size_t)bt * 4096;

  floatx4 acc[2][4] = {};

  for (int c13 = 0; c13 < 13; ++c13) {
    const bool gcn = (c13 < 11);
    const u16* Asrc = gcn ? ANB : T2B;
    const int astr = gcn ? 352 : 64;
    const int acol = gcn ? c13 * 32 : (c13 - 11) * 32;
    const u16* Bsrc = gcn ? XCT : OFT;
    const int bstr = gcn ? 352 : 64;
    __syncthreads();
    for (int i = tid; i < 512; i += 256) {
      const int row = i >> 2, c8 = (i & 3) * 8;
      const int gr = m0 + row;
      uint4 v = make_uint4(0, 0, 0, 0);
      if (gr < 325)
        v = *(const uint4*)(Asrc + (size_t)gr * astr + acol + c8);
      *(uint4*)&Atile[row * 32 + c8] = v;
    }
    {
      const int d = tid >> 2, c8 = (tid & 3) * 8;
      *(uint4*)&Btile[d * 32 + c8] =
          *(const uint4*)(Bsrc + (size_t)d * bstr + acol + c8);
    }
    __syncthreads();
    short8 af[2], bf_[4];
#pragma unroll
    for (int mi = 0; mi < 2; ++mi)
      af[mi] = *(const short8*)&Atile[(wave * 32 + mi * 16 + lc) * 32 + quad * 8];
#pragma unroll
    for (int ni = 0; ni < 4; ++ni)
      bf_[ni] = *(const short8*)&Btile[(ni * 16 + lc) * 32 + quad * 8];
#pragma unroll
    for (int mi = 0; mi < 2; ++mi)
#pragma unroll
      for (int ni = 0; ni < 4; ++ni)
        acc[mi][ni] = __builtin_amdgcn_mfma_f32_16x16x32_bf16(
            af[mi], bf_[ni], acc[mi][ni], 0, 0, 0);
  }

  const int b = bt / 12, t = bt - b * 12;
  const float sgn = (t & 1) ? -1.f : 1.f;
#pragma unroll
  for (int ni = 0; ni < 4; ++ni) {
    const int d = ni * 16 + lc;
    const float bias = bmlp[d];
#pragma unroll
    for (int mi = 0; mi < 2; ++mi) {
#pragma unroll
      for (int reg = 0; reg < 4; ++reg) {
        const int n = m0 + wave * 32 + mi * 16 + quad * 4 + reg;
        if (n >= 325) continue;
        const float v = ws[OFF_VT + ((size_t)b * 3900 + (size_t)n * 12 + t) * 64 + d];
        const float al = ws[OFF_ALT + ((size_t)b * 325 + n) * 64 + d];
        const float te = (v - sgn * al * (1.f / 12.f)) * (1.f / 6.f);
        out[((size_t)bt * 325 + n) * 64 + d] = acc[mi][ni][reg] + bias + te;
      }
    }
  }
}

extern "C" void kernel_launch(void* const* d_in, const int* in_sizes, int n_in,
                              void* d_out, int out_size, void* d_ws, size_t ws_size,
                              hipStream_t stream) {
  const float* x = (const float*)d_in[0];
  const float* adj = (const float*)d_in[1];
  const float* Wq_g = (const float*)d_in[2];
  const float* Wk_g = (const float*)d_in[3];
  const float* Wv_g = (const float*)d_in[4];
  // d_in[5], d_in[6] (Wq_t, Wk_t), d_in[12] (weights_Q_t), d_in[14] (t_modes):
  // dead code — temporal softmax axis == mean axis => out = vf/6.
  const float* Wv_t = (const float*)d_in[7];
  const float* Wfc1 = (const float*)d_in[8];
  const float* Wmlp = (const float*)d_in[9];
  const float* bmlp = (const float*)d_in[10];
  const float* wQ = (const float*)d_in[11];
  const int* sp_modes = (const int*)d_in[13];
  float* ws = (float*)d_ws;
  float* out = (float*)d_out;

  (void)in_sizes; (void)n_in; (void)out_size; (void)ws_size;

  hipMemsetAsync(ws + OFF_NORM, 0, 2 * sizeof(float), stream);
  hipMemsetAsync(ws + OFF_XCT, 0, (size_t)384 * 22528 * sizeof(u16), stream);  // zero n-pads
  k_prep<<<366, 256, 0, stream>>>(adj, Wmlp, Wfc1, wQ, sp_modes, ws);
  k_linear2<<<975, 256, 0, stream>>>(x, Wv_t, Wq_g, Wk_g, ws);
  k_spatial3<<<384, 256, 0, stream>>>(x, Wq_g, Wk_g, Wv_g, ws);
  k_alt<<<2600, 256, 0, stream>>>(ws);
  k_final2<<<1152, 256, 0, stream>>>(bmlp, ws, out);
}